// Round 1
// baseline (33673.889 us; speedup 1.0000x reference)
//
#include <hip/hip_runtime.h>

#define NN 50000
#define NE 800000
static constexpr float BN_EPS = 1e-5f;

// ---------------- CSR build ----------------
__global__ void k_histo(const int* __restrict__ dst, int* __restrict__ deg) {
  int e = blockIdx.x * 256 + threadIdx.x;
  if (e < NE) atomicAdd(&deg[dst[e]], 1);
}

// single-block exclusive scan over 50000 degrees -> row_ptr[0..NN]
__global__ void k_scan(const int* __restrict__ deg, int* __restrict__ row_ptr) {
  __shared__ int ts[1024];
  int t = threadIdx.x;
  const int PER = (NN + 1023) / 1024;  // 49
  int base = t * PER;
  int s = 0;
  for (int i = 0; i < PER; ++i) { int idx = base + i; if (idx < NN) s += deg[idx]; }
  ts[t] = s;
  __syncthreads();
  for (int off = 1; off < 1024; off <<= 1) {
    int v = 0;
    if (t >= off) v = ts[t - off];
    __syncthreads();
    if (t >= off) ts[t] += v;
    __syncthreads();
  }
  int run = (t == 0) ? 0 : ts[t - 1];
  for (int i = 0; i < PER; ++i) {
    int idx = base + i;
    if (idx < NN) { row_ptr[idx] = run; run += deg[idx]; }
  }
  if (t == 1023) row_ptr[NN] = run;
}

__global__ void k_scatter(const int* __restrict__ src, const int* __restrict__ dst,
                          const int* __restrict__ row_ptr, int* __restrict__ cursor,
                          int* __restrict__ col) {
  int e = blockIdx.x * 256 + threadIdx.x;
  if (e >= NE) return;
  int d = dst[e];
  int p = atomicAdd(&cursor[d], 1);
  col[row_ptr[d] + p] = src[e];
}

// ---------------- weight transpose: W[N][K] -> WT[K][N] ----------------
__global__ void k_transpose(const float* __restrict__ W, float* __restrict__ WT, int N, int K) {
  int i = blockIdx.x * 256 + threadIdx.x;
  if (i >= N * K) return;
  int c = i / K, k = i - c * K;
  WT[k * N + c] = W[i];
}

// ---------------- mean aggregation (wave per node, lane = feature) ----------------
__global__ void k_aggregate(const float* __restrict__ feat, int fstride, int d,
                            const int* __restrict__ row_ptr, const int* __restrict__ col,
                            float* __restrict__ agg, int astride) {
  int node = blockIdx.x * 4 + (threadIdx.x >> 6);
  if (node >= NN) return;
  int lane = threadIdx.x & 63;
  int beg = row_ptr[node], end = row_ptr[node + 1];
  float acc[4] = {0.f, 0.f, 0.f, 0.f};
  for (int j = beg; j < end; ++j) {
    int s = col[j];
    const float* fr = feat + (size_t)s * fstride;
#pragma unroll
    for (int i = 0; i < 4; ++i) {
      int f = lane + i * 64;
      if (f < d) acc[i] += fr[f];
    }
  }
  float inv = 1.0f / fmaxf((float)(end - beg), 1.0f);
#pragma unroll
  for (int i = 0; i < 4; ++i) {
    int f = lane + i * 64;
    if (f < d) agg[(size_t)node * astride + f] = acc[i] * inv;
  }
}

// ---------------- fused SAGE GEMM: out = A1@W1T + A2@W2T + b ----------------
// thread = output column c, R rows accumulated in registers; W read coalesced [K][N]
template <int N, int R, bool A2V2>
__global__ void k_gemm(const float* __restrict__ A1, int s1,
                       const float* __restrict__ A2, int s2,
                       const float* __restrict__ W1T, const float* __restrict__ W2T,
                       const float* __restrict__ bias,
                       float* __restrict__ out, int K) {
  constexpr int G = 256 / N;
  constexpr int ROWS = R * G;
  int c = threadIdx.x % N;
  int g = threadIdx.x / N;
  int row0 = blockIdx.x * ROWS + g * R;
  float acc[R];
#pragma unroll
  for (int r = 0; r < R; ++r) acc[r] = 0.f;

  int K4 = K & ~3;
  for (int k = 0; k < K4; k += 4) {
    float wl0 = W1T[(k + 0) * N + c], wl1 = W1T[(k + 1) * N + c];
    float wl2 = W1T[(k + 2) * N + c], wl3 = W1T[(k + 3) * N + c];
    float wr0 = W2T[(k + 0) * N + c], wr1 = W2T[(k + 1) * N + c];
    float wr2 = W2T[(k + 2) * N + c], wr3 = W2T[(k + 3) * N + c];
#pragma unroll
    for (int r = 0; r < R; ++r) {
      int row = row0 + r;
      if (row < NN) {
        const float* p1 = A1 + (size_t)row * s1 + k;
        float4 a1 = *reinterpret_cast<const float4*>(p1);
        const float* p2 = A2 + (size_t)row * s2 + k;
        float b0, b1, b2, b3;
        if constexpr (A2V2) {  // 8B-aligned rows only (stride 166)
          float2 u = *reinterpret_cast<const float2*>(p2);
          float2 v = *reinterpret_cast<const float2*>(p2 + 2);
          b0 = u.x; b1 = u.y; b2 = v.x; b3 = v.y;
        } else {
          float4 a2 = *reinterpret_cast<const float4*>(p2);
          b0 = a2.x; b1 = a2.y; b2 = a2.z; b3 = a2.w;
        }
        acc[r] += a1.x * wl0 + a1.y * wl1 + a1.z * wl2 + a1.w * wl3
                + b0 * wr0 + b1 * wr1 + b2 * wr2 + b3 * wr3;
      }
    }
  }
  for (int k = K4; k < K; ++k) {
    float wl = W1T[k * N + c];
    float wr = W2T[k * N + c];
#pragma unroll
    for (int r = 0; r < R; ++r) {
      int row = row0 + r;
      if (row < NN) acc[r] += A1[(size_t)row * s1 + k] * wl + A2[(size_t)row * s2 + k] * wr;
    }
  }
  float b = bias[c];
#pragma unroll
  for (int r = 0; r < R; ++r) {
    int row = row0 + r;
    if (row < NN) out[(size_t)row * N + c] = acc[r] + b;
  }
}

// ---------------- BatchNorm ----------------
__global__ void k_bn_stats(const float* __restrict__ h, float* __restrict__ acc, int N) {
  int c = threadIdx.x;  // blockDim == N
  int rows = (NN + gridDim.x - 1) / gridDim.x;
  int r0 = blockIdx.x * rows, r1 = min(r0 + rows, NN);
  float s = 0.f, s2 = 0.f;
  for (int r = r0; r < r1; ++r) {
    float v = h[(size_t)r * N + c];
    s += v; s2 += v * v;
  }
  atomicAdd(&acc[c], s);
  atomicAdd(&acc[N + c], s2);
}

__global__ void k_bn_apply(float* __restrict__ h, const float* __restrict__ acc,
                           const float* __restrict__ g, const float* __restrict__ b, int N) {
  int i = blockIdx.x * 256 + threadIdx.x;
  if (i >= NN * N) return;
  int c = i % N;
  float mean = acc[c] * (1.0f / NN);
  float var = acc[N + c] * (1.0f / NN) - mean * mean;
  float sc = g[c] * rsqrtf(var + BN_EPS);
  float sh = b[c] - mean * sc;
  float v = h[i] * sc + sh;
  h[i] = v > 0.f ? v : 0.f;
}

// ---------------- classifier ----------------
__global__ void k_classifier(const float* __restrict__ emb, const float* __restrict__ Wc,
                             const float* __restrict__ bc, float* __restrict__ logits) {
  int row = blockIdx.x * 256 + threadIdx.x;
  if (row >= NN) return;
  const float* e = emb + (size_t)row * 64;
  float s0 = bc[0], s1 = bc[1];
#pragma unroll
  for (int k = 0; k < 64; ++k) { float v = e[k]; s0 += v * Wc[k]; s1 += v * Wc[64 + k]; }
  logits[row * 2 + 0] = s0;
  logits[row * 2 + 1] = s1;
}

extern "C" void kernel_launch(void* const* d_in, const int* in_sizes, int n_in,
                              void* d_out, int out_size, void* d_ws, size_t ws_size,
                              hipStream_t stream) {
  const float* x   = (const float*)d_in[0];
  const int* ei    = (const int*)d_in[1];
  const float* Wl1 = (const float*)d_in[2];
  const float* Wr1 = (const float*)d_in[3];
  const float* b1  = (const float*)d_in[4];
  const float* Wl2 = (const float*)d_in[5];
  const float* Wr2 = (const float*)d_in[6];
  const float* b2  = (const float*)d_in[7];
  const float* Wle = (const float*)d_in[8];
  const float* Wre = (const float*)d_in[9];
  const float* be  = (const float*)d_in[10];
  const float* g1  = (const float*)d_in[11];
  const float* bt1 = (const float*)d_in[12];
  const float* g2  = (const float*)d_in[13];
  const float* bt2 = (const float*)d_in[14];
  const float* Wc  = (const float*)d_in[15];
  const float* bc  = (const float*)d_in[16];

  const int* src = ei;        // edge_index[0]
  const int* dst = ei + NE;   // edge_index[1]

  char* ws = (char*)d_ws;
  size_t off = 0;
  auto take = [&](size_t bytes) -> char* {
    char* p = ws + off;
    off = (off + bytes + 255) & ~(size_t)255;
    return p;
  };
  int* deg      = (int*)take((size_t)NN * 4);
  int* row_ptr  = (int*)take((size_t)(NN + 1) * 4);
  int* cursor   = (int*)take((size_t)NN * 4);
  int* col      = (int*)take((size_t)NE * 4);
  float* wlt1   = (float*)take((size_t)166 * 256 * 4);
  float* wrt1   = (float*)take((size_t)166 * 256 * 4);
  float* wlt2   = (float*)take((size_t)256 * 128 * 4);
  float* wrt2   = (float*)take((size_t)256 * 128 * 4);
  float* wlt3   = (float*)take((size_t)128 * 64 * 4);
  float* wrt3   = (float*)take((size_t)128 * 64 * 4);
  float* bnacc  = (float*)take(512 * 4);
  float* agg    = (float*)take((size_t)NN * 256 * 4);
  float* h1     = (float*)take((size_t)NN * 256 * 4);
  float* h2     = (float*)take((size_t)NN * 128 * 4);

  float* logits = (float*)d_out;
  float* emb    = (float*)d_out + (size_t)NN * 2;

  // CSR build (per call; atomics only on ints)
  hipMemsetAsync(deg, 0, (size_t)NN * 4, stream);
  k_histo<<<(NE + 255) / 256, 256, 0, stream>>>(dst, deg);
  k_scan<<<1, 1024, 0, stream>>>(deg, row_ptr);
  hipMemsetAsync(cursor, 0, (size_t)NN * 4, stream);
  k_scatter<<<(NE + 255) / 256, 256, 0, stream>>>(src, dst, row_ptr, cursor, col);

  // weight transposes
  k_transpose<<<(256 * 166 + 255) / 256, 256, 0, stream>>>(Wl1, wlt1, 256, 166);
  k_transpose<<<(256 * 166 + 255) / 256, 256, 0, stream>>>(Wr1, wrt1, 256, 166);
  k_transpose<<<(128 * 256 + 255) / 256, 256, 0, stream>>>(Wl2, wlt2, 128, 256);
  k_transpose<<<(128 * 256 + 255) / 256, 256, 0, stream>>>(Wr2, wrt2, 128, 256);
  k_transpose<<<(64 * 128 + 255) / 256, 256, 0, stream>>>(Wle, wlt3, 64, 128);
  k_transpose<<<(64 * 128 + 255) / 256, 256, 0, stream>>>(Wre, wrt3, 64, 128);

  // ---- layer 1: 166 -> 256, BN+ReLU ----
  k_aggregate<<<(NN + 3) / 4, 256, 0, stream>>>(x, 166, 166, row_ptr, col, agg, 168);
  k_gemm<256, 32, true><<<(NN + 31) / 32, 256, 0, stream>>>(agg, 168, x, 166, wlt1, wrt1, b1, h1, 166);
  hipMemsetAsync(bnacc, 0, 512 * 4, stream);
  k_bn_stats<<<256, 256, 0, stream>>>(h1, bnacc, 256);
  k_bn_apply<<<(NN * 256 + 255) / 256, 256, 0, stream>>>(h1, bnacc, g1, bt1, 256);

  // ---- layer 2: 256 -> 128, BN+ReLU ----
  k_aggregate<<<(NN + 3) / 4, 256, 0, stream>>>(h1, 256, 256, row_ptr, col, agg, 256);
  k_gemm<128, 16, false><<<(NN + 31) / 32, 256, 0, stream>>>(agg, 256, h1, 256, wlt2, wrt2, b2, h2, 256);
  hipMemsetAsync(bnacc, 0, 512 * 4, stream);
  k_bn_stats<<<256, 128, 0, stream>>>(h2, bnacc, 128);
  k_bn_apply<<<(NN * 128 + 255) / 256, 256, 0, stream>>>(h2, bnacc, g2, bt2, 128);

  // ---- layer 3: 128 -> 64 (embeddings), then classifier ----
  k_aggregate<<<(NN + 3) / 4, 256, 0, stream>>>(h2, 128, 128, row_ptr, col, agg, 128);
  k_gemm<64, 8, false><<<(NN + 31) / 32, 256, 0, stream>>>(agg, 128, h2, 128, wlt3, wrt3, be, emb, 128);
  k_classifier<<<(NN + 255) / 256, 256, 0, stream>>>(emb, Wc, bc, logits);
}

// Round 2
// 1092.936 us; speedup vs baseline: 30.8105x; 30.8105x over previous
//
#include <hip/hip_runtime.h>

#define NN 50000
#define NE 800000
static constexpr float BN_EPS = 1e-5f;

// ---------------- CSR build ----------------
__global__ void k_histo(const int* __restrict__ dst, int* __restrict__ deg) {
  int e = blockIdx.x * 256 + threadIdx.x;
  if (e < NE) atomicAdd(&deg[dst[e]], 1);
}

__global__ void k_scan(const int* __restrict__ deg, int* __restrict__ row_ptr) {
  __shared__ int ts[1024];
  int t = threadIdx.x;
  const int PER = (NN + 1023) / 1024;  // 49
  int base = t * PER;
  int s = 0;
  for (int i = 0; i < PER; ++i) { int idx = base + i; if (idx < NN) s += deg[idx]; }
  ts[t] = s;
  __syncthreads();
  for (int off = 1; off < 1024; off <<= 1) {
    int v = 0;
    if (t >= off) v = ts[t - off];
    __syncthreads();
    if (t >= off) ts[t] += v;
    __syncthreads();
  }
  int run = (t == 0) ? 0 : ts[t - 1];
  for (int i = 0; i < PER; ++i) {
    int idx = base + i;
    if (idx < NN) { row_ptr[idx] = run; run += deg[idx]; }
  }
  if (t == 1023) row_ptr[NN] = run;
}

__global__ void k_scatter(const int* __restrict__ src, const int* __restrict__ dst,
                          const int* __restrict__ row_ptr, int* __restrict__ cursor,
                          int* __restrict__ col) {
  int e = blockIdx.x * 256 + threadIdx.x;
  if (e >= NE) return;
  int d = dst[e];
  int p = atomicAdd(&cursor[d], 1);
  col[row_ptr[d] + p] = src[e];
}

// ---------------- pack x into XC1 cols 166..335 (168..333 = x, rest zero) ----------------
__global__ void k_pack_x(const float* __restrict__ x, float* __restrict__ XC1) {
  int row = blockIdx.x;
  int t = threadIdx.x;
  if (t >= 170) return;
  int c = 166 + t;  // 166..335
  float v = 0.f;
  if (c >= 168 && c < 334) v = x[(size_t)row * 166 + (c - 168)];
  XC1[(size_t)row * 336 + c] = v;
}

// ---------------- stack Wl^T / Wr^T -> WC [2*Kpad][N] (row-major), zero-padded ----------
__global__ void k_pack_w(const float* __restrict__ Wl, const float* __restrict__ Wr,
                         float* __restrict__ WC, int K, int Kpad, int N) {
  int idx = blockIdx.x * 256 + threadIdx.x;
  int total = 2 * Kpad * N;
  if (idx >= total) return;
  int r = idx / N, c = idx - r * N;
  float v = 0.f;
  if (r < Kpad) {
    if (r < K) v = Wl[(size_t)c * K + r];
  } else {
    int k = r - Kpad;
    if (k < K) v = Wr[(size_t)c * K + k];
  }
  WC[idx] = v;
}

// ---------------- mean aggregation (wave per node, lane = feature) ----------------
__global__ void k_aggregate(const float* __restrict__ feat, int fstride, int d,
                            const int* __restrict__ row_ptr, const int* __restrict__ col,
                            float* __restrict__ agg, int astride) {
  int node = blockIdx.x * 4 + (threadIdx.x >> 6);
  if (node >= NN) return;
  int lane = threadIdx.x & 63;
  int beg = row_ptr[node], end = row_ptr[node + 1];
  float acc[4] = {0.f, 0.f, 0.f, 0.f};
  for (int j = beg; j < end; ++j) {
    int s = col[j];
    const float* fr = feat + (size_t)s * fstride;
#pragma unroll
    for (int i = 0; i < 4; ++i) {
      int f = lane + i * 64;
      if (f < d) acc[i] += fr[f];
    }
  }
  float inv = 1.0f / fmaxf((float)(end - beg), 1.0f);
#pragma unroll
  for (int i = 0; i < 4; ++i) {
    int f = lane + i * 64;
    if (f < d) agg[(size_t)node * astride + f] = acc[i] * inv;
  }
}

// ---------------- tiled fp32 GEMM: out[M x N] = A[M x KC] @ W[KC x N] + bias ----------
// BM=64, BN=64, BK=16, 256 threads, 4x4 register micro-tile (statically indexed).
__global__ __launch_bounds__(256) void k_gemm_t(
    const float* __restrict__ A, int KC,
    const float* __restrict__ W, const float* __restrict__ bias,
    float* __restrict__ out, int Ntot) {
  __shared__ float As[16][68];  // [k][m], padded stride 68 (16B-aligned rows)
  __shared__ float Ws[16][64];  // [k][n]
  int tx = threadIdx.x % 16, ty = threadIdx.x / 16;
  int m0 = blockIdx.x * 64, n0 = blockIdx.y * 64;

  int sm = threadIdx.x / 4;         // A-stage row 0..63
  int sk = (threadIdx.x % 4) * 4;   // A-stage k 0,4,8,12
  int wk = threadIdx.x / 16;        // W-stage k 0..15
  int wn = (threadIdx.x % 16) * 4;  // W-stage n

  float acc[4][4];
#pragma unroll
  for (int i = 0; i < 4; ++i)
#pragma unroll
    for (int j = 0; j < 4; ++j) acc[i][j] = 0.f;

  int arow = m0 + sm;
  const float* aptr = A + (size_t)arow * KC + sk;
  const float* wptr = W + (size_t)wk * Ntot + n0 + wn;

  for (int k0 = 0; k0 < KC; k0 += 16) {
    float4 av = (arow < NN) ? *reinterpret_cast<const float4*>(aptr + k0)
                            : float4{0.f, 0.f, 0.f, 0.f};
    float4 wv = *reinterpret_cast<const float4*>(wptr + (size_t)k0 * Ntot);
    __syncthreads();
    As[sk + 0][sm] = av.x;
    As[sk + 1][sm] = av.y;
    As[sk + 2][sm] = av.z;
    As[sk + 3][sm] = av.w;
    *reinterpret_cast<float4*>(&Ws[wk][wn]) = wv;
    __syncthreads();
#pragma unroll
    for (int k = 0; k < 16; ++k) {
      float4 a = *reinterpret_cast<const float4*>(&As[k][ty * 4]);
      float4 w = *reinterpret_cast<const float4*>(&Ws[k][tx * 4]);
      acc[0][0] += a.x * w.x; acc[0][1] += a.x * w.y; acc[0][2] += a.x * w.z; acc[0][3] += a.x * w.w;
      acc[1][0] += a.y * w.x; acc[1][1] += a.y * w.y; acc[1][2] += a.y * w.z; acc[1][3] += a.y * w.w;
      acc[2][0] += a.z * w.x; acc[2][1] += a.z * w.y; acc[2][2] += a.z * w.z; acc[2][3] += a.z * w.w;
      acc[3][0] += a.w * w.x; acc[3][1] += a.w * w.y; acc[3][2] += a.w * w.z; acc[3][3] += a.w * w.w;
    }
  }

  float4 bv = *reinterpret_cast<const float4*>(bias + n0 + tx * 4);
#pragma unroll
  for (int i = 0; i < 4; ++i) {
    int row = m0 + ty * 4 + i;
    if (row < NN) {
      float4 o;
      o.x = acc[i][0] + bv.x; o.y = acc[i][1] + bv.y;
      o.z = acc[i][2] + bv.z; o.w = acc[i][3] + bv.w;
      *reinterpret_cast<float4*>(out + (size_t)row * Ntot + n0 + tx * 4) = o;
    }
  }
}

// ---------------- BatchNorm ----------------
template <int N>
__global__ void k_bn_stats(const float* __restrict__ h, float* __restrict__ acc) {
  int c = threadIdx.x;  // blockDim == N
  int rows = (NN + gridDim.x - 1) / gridDim.x;
  int r0 = blockIdx.x * rows, r1 = min(r0 + rows, NN);
  float s = 0.f, s2 = 0.f;
  for (int r = r0; r < r1; ++r) {
    float v = h[(size_t)r * N + c];
    s += v; s2 += v * v;
  }
  atomicAdd(&acc[c], s);
  atomicAdd(&acc[N + c], s2);
}

// normalize + ReLU, write into packed next-layer buffer at column offset XOFF, stride XST
template <int N, int XST, int XOFF>
__global__ void k_bn_apply(const float* __restrict__ h, const float* __restrict__ acc,
                           const float* __restrict__ g, const float* __restrict__ b,
                           float* __restrict__ XC) {
  int idx = blockIdx.x * 256 + threadIdx.x;
  if (idx >= NN * N) return;
  int row = idx / N, c = idx - row * N;
  float mean = acc[c] * (1.0f / NN);
  float var = acc[N + c] * (1.0f / NN) - mean * mean;
  float sc = g[c] * rsqrtf(var + BN_EPS);
  float sh = b[c] - mean * sc;
  float v = h[idx] * sc + sh;
  XC[(size_t)row * XST + XOFF + c] = v > 0.f ? v : 0.f;
}

// ---------------- classifier ----------------
__global__ void k_classifier(const float* __restrict__ emb, const float* __restrict__ Wc,
                             const float* __restrict__ bc, float* __restrict__ logits) {
  int row = blockIdx.x * 256 + threadIdx.x;
  if (row >= NN) return;
  const float* e = emb + (size_t)row * 64;
  float s0 = bc[0], s1 = bc[1];
#pragma unroll
  for (int k = 0; k < 64; ++k) { float v = e[k]; s0 += v * Wc[k]; s1 += v * Wc[64 + k]; }
  logits[row * 2 + 0] = s0;
  logits[row * 2 + 1] = s1;
}

extern "C" void kernel_launch(void* const* d_in, const int* in_sizes, int n_in,
                              void* d_out, int out_size, void* d_ws, size_t ws_size,
                              hipStream_t stream) {
  const float* x   = (const float*)d_in[0];
  const int* ei    = (const int*)d_in[1];
  const float* Wl1 = (const float*)d_in[2];
  const float* Wr1 = (const float*)d_in[3];
  const float* b1  = (const float*)d_in[4];
  const float* Wl2 = (const float*)d_in[5];
  const float* Wr2 = (const float*)d_in[6];
  const float* b2  = (const float*)d_in[7];
  const float* Wle = (const float*)d_in[8];
  const float* Wre = (const float*)d_in[9];
  const float* be  = (const float*)d_in[10];
  const float* g1  = (const float*)d_in[11];
  const float* bt1 = (const float*)d_in[12];
  const float* g2  = (const float*)d_in[13];
  const float* bt2 = (const float*)d_in[14];
  const float* Wc  = (const float*)d_in[15];
  const float* bc  = (const float*)d_in[16];

  const int* src = ei;        // edge_index[0]
  const int* dst = ei + NE;   // edge_index[1]

  char* ws = (char*)d_ws;
  size_t off = 0;
  auto take = [&](size_t bytes) -> char* {
    char* p = ws + off;
    off = (off + bytes + 255) & ~(size_t)255;
    return p;
  };
  int* deg      = (int*)take((size_t)NN * 4);
  int* row_ptr  = (int*)take((size_t)(NN + 1) * 4);
  int* cursor   = (int*)take((size_t)NN * 4);
  int* col      = (int*)take((size_t)NE * 4);
  float* w1c    = (float*)take((size_t)336 * 256 * 4);
  float* w2c    = (float*)take((size_t)512 * 128 * 4);
  float* w3c    = (float*)take((size_t)256 * 64 * 4);
  float* bnacc  = (float*)take(512 * 4);
  float* R0     = (float*)take((size_t)NN * 512 * 4);  // XC1(336)/XC2(512)/XC3(256)
  float* R1     = (float*)take((size_t)NN * 256 * 4);  // h1raw(256)/h2raw(128)

  float* XC1 = R0;  // [NN][336]: agg1 | pad2 | x | pad2
  float* XC2 = R0;  // [NN][512]: agg2 | h1
  float* XC3 = R0;  // [NN][256]: agg3 | h2
  float* h1  = R1;  // [NN][256]
  float* h2  = R1;  // [NN][128]

  float* logits = (float*)d_out;
  float* emb    = (float*)d_out + (size_t)NN * 2;

  // CSR build
  hipMemsetAsync(deg, 0, (size_t)NN * 4, stream);
  k_histo<<<(NE + 255) / 256, 256, 0, stream>>>(dst, deg);
  k_scan<<<1, 1024, 0, stream>>>(deg, row_ptr);
  hipMemsetAsync(cursor, 0, (size_t)NN * 4, stream);
  k_scatter<<<(NE + 255) / 256, 256, 0, stream>>>(src, dst, row_ptr, cursor, col);

  // weight packing
  k_pack_w<<<(2 * 168 * 256 + 255) / 256, 256, 0, stream>>>(Wl1, Wr1, w1c, 166, 168, 256);
  k_pack_w<<<(2 * 256 * 128 + 255) / 256, 256, 0, stream>>>(Wl2, Wr2, w2c, 256, 256, 128);
  k_pack_w<<<(2 * 128 * 64 + 255) / 256, 256, 0, stream>>>(Wle, Wre, w3c, 128, 128, 64);

  // ---- layer 1: [agg1 | x] (KC=336) @ w1c -> h1 [NN][256]; BN+ReLU -> XC2 right ----
  k_pack_x<<<NN, 192, 0, stream>>>(x, XC1);
  k_aggregate<<<(NN + 3) / 4, 256, 0, stream>>>(x, 166, 166, row_ptr, col, XC1, 336);
  {
    dim3 g((NN + 63) / 64, 256 / 64);
    k_gemm_t<<<g, 256, 0, stream>>>(XC1, 336, w1c, b1, h1, 256);
  }
  hipMemsetAsync(bnacc, 0, 512 * 4, stream);
  k_bn_stats<256><<<256, 256, 0, stream>>>(h1, bnacc);
  k_bn_apply<256, 512, 256><<<(NN * 256 + 255) / 256, 256, 0, stream>>>(h1, bnacc, g1, bt1, XC2);

  // ---- layer 2: [agg2 | h1] (KC=512) @ w2c -> h2 [NN][128]; BN+ReLU -> XC3 right ----
  k_aggregate<<<(NN + 3) / 4, 256, 0, stream>>>(XC2 + 256, 512, 256, row_ptr, col, XC2, 512);
  {
    dim3 g((NN + 63) / 64, 128 / 64);
    k_gemm_t<<<g, 256, 0, stream>>>(XC2, 512, w2c, b2, h2, 128);
  }
  hipMemsetAsync(bnacc, 0, 512 * 4, stream);
  k_bn_stats<128><<<256, 128, 0, stream>>>(h2, bnacc);
  k_bn_apply<128, 256, 128><<<(NN * 128 + 255) / 256, 256, 0, stream>>>(h2, bnacc, g2, bt2, XC3);

  // ---- layer 3: [agg3 | h2] (KC=256) @ w3c -> emb [NN][64]; classifier ----
  k_aggregate<<<(NN + 3) / 4, 256, 0, stream>>>(XC3 + 128, 256, 128, row_ptr, col, XC3, 256);
  {
    dim3 g((NN + 63) / 64, 1);
    k_gemm_t<<<g, 256, 0, stream>>>(XC3, 256, w3c, be, emb, 64);
  }
  k_classifier<<<(NN + 255) / 256, 256, 0, stream>>>(emb, Wc, bc, logits);
}

// Round 4
// 756.767 us; speedup vs baseline: 44.4971x; 1.4442x over previous
//
#include <hip/hip_runtime.h>

#define NN 50000
#define NE 800000
static constexpr float BN_EPS = 1e-5f;

// ---------------- CSR build ----------------
__global__ void k_histo(const int* __restrict__ dst, int* __restrict__ deg) {
  int e = blockIdx.x * 256 + threadIdx.x;
  if (e < NE) atomicAdd(&deg[dst[e]], 1);
}

__global__ void k_scan(const int* __restrict__ deg, int* __restrict__ row_ptr) {
  __shared__ int ts[1024];
  int t = threadIdx.x;
  const int PER = (NN + 1023) / 1024;  // 49
  int base = t * PER;
  int s = 0;
  for (int i = 0; i < PER; ++i) { int idx = base + i; if (idx < NN) s += deg[idx]; }
  ts[t] = s;
  __syncthreads();
  for (int off = 1; off < 1024; off <<= 1) {
    int v = 0;
    if (t >= off) v = ts[t - off];
    __syncthreads();
    if (t >= off) ts[t] += v;
    __syncthreads();
  }
  int run = (t == 0) ? 0 : ts[t - 1];
  for (int i = 0; i < PER; ++i) {
    int idx = base + i;
    if (idx < NN) { row_ptr[idx] = run; run += deg[idx]; }
  }
  if (t == 1023) row_ptr[NN] = run;
}

__global__ void k_scatter(const int* __restrict__ src, const int* __restrict__ dst,
                          const int* __restrict__ row_ptr, int* __restrict__ cursor,
                          int* __restrict__ col) {
  int e = blockIdx.x * 256 + threadIdx.x;
  if (e >= NE) return;
  int d = dst[e];
  int p = atomicAdd(&cursor[d], 1);
  col[row_ptr[d] + p] = src[e];
}

// ---------------- pack x into XC1 cols 166..335 (168..333 = x, rest zero) ----------------
__global__ void k_pack_x(const float* __restrict__ x, float* __restrict__ XC1) {
  int row = blockIdx.x;
  int t = threadIdx.x;
  if (t >= 170) return;
  int c = 166 + t;  // 166..335
  float v = 0.f;
  if (c >= 168 && c < 334) v = x[(size_t)row * 166 + (c - 168)];
  XC1[(size_t)row * 336 + c] = v;
}

// ---- stack Wl^T / Wr^T along K -> WC [2*Kpad][N], zero-padded (layer 1) ----
__global__ void k_pack_w(const float* __restrict__ Wl, const float* __restrict__ Wr,
                         float* __restrict__ WC, int K, int Kpad, int N) {
  int idx = blockIdx.x * 256 + threadIdx.x;
  int total = 2 * Kpad * N;
  if (idx >= total) return;
  int r = idx / N, c = idx - r * N;
  float v = 0.f;
  if (r < Kpad) {
    if (r < K) v = Wl[(size_t)c * K + r];
  } else {
    int k = r - Kpad;
    if (k < K) v = Wr[(size_t)c * K + k];
  }
  WC[idx] = v;
}

// ---- stack Wl^T | Wr^T along N -> WC [K][2*Nh] (layers 2,3: pre-multiply form) ----
__global__ void k_pack_w_n(const float* __restrict__ Wl, const float* __restrict__ Wr,
                           float* __restrict__ WC, int K, int Nh) {
  int idx = blockIdx.x * 256 + threadIdx.x;
  int total = K * 2 * Nh;
  if (idx >= total) return;
  int r = idx / (2 * Nh), c = idx - r * (2 * Nh);
  WC[idx] = (c < Nh) ? Wl[(size_t)c * K + r] : Wr[(size_t)(c - Nh) * K + r];
}

// ---------------- mean aggregation (wave per node, lane = feature), U-edge unroll ----
// FUSE: out = mean + self + bias (self-projection already computed by GEMM)
template <int D, int U, bool FUSE>
__global__ __launch_bounds__(256) void k_agg(
    const float* __restrict__ feat, int fs,
    const int* __restrict__ row_ptr, const int* __restrict__ col,
    const float* __restrict__ self, int ss,
    const float* __restrict__ bias,
    float* __restrict__ out, int os) {
  constexpr int C = (D + 63) / 64;
  int node = blockIdx.x * 4 + (threadIdx.x >> 6);
  if (node >= NN) return;
  int lane = threadIdx.x & 63;
  int beg = row_ptr[node], end = row_ptr[node + 1];
  float acc[C];
#pragma unroll
  for (int c = 0; c < C; ++c) acc[c] = 0.f;

  int j = beg;
  for (; j + U <= end; j += U) {
    const float* fp[U];
#pragma unroll
    for (int u = 0; u < U; ++u) fp[u] = feat + (size_t)col[j + u] * fs;
#pragma unroll
    for (int c = 0; c < C; ++c) {
      int f = lane + c * 64;
      float t[U];
#pragma unroll
      for (int u = 0; u < U; ++u) t[u] = (f < D) ? fp[u][f] : 0.f;
      float s = 0.f;
#pragma unroll
      for (int u = 0; u < U; ++u) s += t[u];
      acc[c] += s;
    }
  }
  for (; j < end; ++j) {
    const float* fr = feat + (size_t)col[j] * fs;
#pragma unroll
    for (int c = 0; c < C; ++c) {
      int f = lane + c * 64;
      if (f < D) acc[c] += fr[f];
    }
  }
  float inv = 1.0f / fmaxf((float)(end - beg), 1.0f);
#pragma unroll
  for (int c = 0; c < C; ++c) {
    int f = lane + c * 64;
    if (f < D) {
      float v = acc[c] * inv;
      if constexpr (FUSE) v += self[(size_t)node * ss + f] + bias[f];
      out[(size_t)node * os + f] = v;
    }
  }
}

// ---------------- tiled fp32 GEMM: out[M x N] = A[M x KC] @ W[KC x N] (+ bias) ------
// BM=64, BN=64, BK=16, 256 threads, 4x4 register micro-tile (statically indexed).
template <bool BIASED>
__global__ __launch_bounds__(256) void k_gemm_t(
    const float* __restrict__ A, int KC,
    const float* __restrict__ W, const float* __restrict__ bias,
    float* __restrict__ out, int Ntot) {
  __shared__ float As[16][68];  // [k][m], padded
  __shared__ float Ws[16][64];  // [k][n]
  int tx = threadIdx.x % 16, ty = threadIdx.x / 16;
  int m0 = blockIdx.x * 64, n0 = blockIdx.y * 64;

  int sm = threadIdx.x / 4;         // A-stage row 0..63
  int sk = (threadIdx.x % 4) * 4;   // A-stage k 0,4,8,12
  int wk = threadIdx.x / 16;        // W-stage k 0..15
  int wn = (threadIdx.x % 16) * 4;  // W-stage n

  float acc[4][4];
#pragma unroll
  for (int i = 0; i < 4; ++i)
#pragma unroll
    for (int j = 0; j < 4; ++j) acc[i][j] = 0.f;

  int arow = m0 + sm;
  const float* aptr = A + (size_t)arow * KC + sk;
  const float* wptr = W + (size_t)wk * Ntot + n0 + wn;

  for (int k0 = 0; k0 < KC; k0 += 16) {
    float4 av = (arow < NN) ? *reinterpret_cast<const float4*>(aptr + k0)
                            : float4{0.f, 0.f, 0.f, 0.f};
    float4 wv = *reinterpret_cast<const float4*>(wptr + (size_t)k0 * Ntot);
    __syncthreads();
    As[sk + 0][sm] = av.x;
    As[sk + 1][sm] = av.y;
    As[sk + 2][sm] = av.z;
    As[sk + 3][sm] = av.w;
    *reinterpret_cast<float4*>(&Ws[wk][wn]) = wv;
    __syncthreads();
#pragma unroll
    for (int k = 0; k < 16; ++k) {
      float4 a = *reinterpret_cast<const float4*>(&As[k][ty * 4]);
      float4 w = *reinterpret_cast<const float4*>(&Ws[k][tx * 4]);
      acc[0][0] += a.x * w.x; acc[0][1] += a.x * w.y; acc[0][2] += a.x * w.z; acc[0][3] += a.x * w.w;
      acc[1][0] += a.y * w.x; acc[1][1] += a.y * w.y; acc[1][2] += a.y * w.z; acc[1][3] += a.y * w.w;
      acc[2][0] += a.z * w.x; acc[2][1] += a.z * w.y; acc[2][2] += a.z * w.z; acc[2][3] += a.z * w.w;
      acc[3][0] += a.w * w.x; acc[3][1] += a.w * w.y; acc[3][2] += a.w * w.z; acc[3][3] += a.w * w.w;
    }
  }

  float4 bv = {0.f, 0.f, 0.f, 0.f};
  if constexpr (BIASED) bv = *reinterpret_cast<const float4*>(bias + n0 + tx * 4);
#pragma unroll
  for (int i = 0; i < 4; ++i) {
    int row = m0 + ty * 4 + i;
    if (row < NN) {
      float4 o;
      o.x = acc[i][0] + bv.x; o.y = acc[i][1] + bv.y;
      o.z = acc[i][2] + bv.z; o.w = acc[i][3] + bv.w;
      *reinterpret_cast<float4*>(out + (size_t)row * Ntot + n0 + tx * 4) = o;
    }
  }
}

// ---------------- BatchNorm ----------------
template <int N>
__global__ void k_bn_stats(const float* __restrict__ h, float* __restrict__ acc) {
  int c = threadIdx.x;  // blockDim == N
  int rows = (NN + gridDim.x - 1) / gridDim.x;
  int r0 = blockIdx.x * rows, r1 = min(r0 + rows, NN);
  float s = 0.f, s2 = 0.f;
  for (int r = r0; r < r1; ++r) {
    float v = h[(size_t)r * N + c];
    s += v; s2 += v * v;
  }
  atomicAdd(&acc[c], s);
  atomicAdd(&acc[N + c], s2);
}

template <int N>
__global__ void k_bn_apply(const float* __restrict__ h, const float* __restrict__ acc,
                           const float* __restrict__ g, const float* __restrict__ b,
                           float* __restrict__ out) {
  int idx = blockIdx.x * 256 + threadIdx.x;
  if (idx >= NN * N) return;
  int c = idx % N;
  float mean = acc[c] * (1.0f / NN);
  float var = acc[N + c] * (1.0f / NN) - mean * mean;
  float sc = g[c] * rsqrtf(var + BN_EPS);
  float sh = b[c] - mean * sc;
  float v = h[idx] * sc + sh;
  out[idx] = v > 0.f ? v : 0.f;
}

// ---------------- classifier ----------------
__global__ void k_classifier(const float* __restrict__ emb, const float* __restrict__ Wc,
                             const float* __restrict__ bc, float* __restrict__ logits) {
  int row = blockIdx.x * 256 + threadIdx.x;
  if (row >= NN) return;
  const float* e = emb + (size_t)row * 64;
  float s0 = bc[0], s1 = bc[1];
#pragma unroll
  for (int k = 0; k < 64; ++k) { float v = e[k]; s0 += v * Wc[k]; s1 += v * Wc[64 + k]; }
  logits[row * 2 + 0] = s0;
  logits[row * 2 + 1] = s1;
}

extern "C" void kernel_launch(void* const* d_in, const int* in_sizes, int n_in,
                              void* d_out, int out_size, void* d_ws, size_t ws_size,
                              hipStream_t stream) {
  const float* x   = (const float*)d_in[0];
  const int* ei    = (const int*)d_in[1];
  const float* Wl1 = (const float*)d_in[2];
  const float* Wr1 = (const float*)d_in[3];
  const float* b1  = (const float*)d_in[4];
  const float* Wl2 = (const float*)d_in[5];
  const float* Wr2 = (const float*)d_in[6];
  const float* b2  = (const float*)d_in[7];
  const float* Wle = (const float*)d_in[8];
  const float* Wre = (const float*)d_in[9];
  const float* be  = (const float*)d_in[10];
  const float* g1  = (const float*)d_in[11];
  const float* bt1 = (const float*)d_in[12];
  const float* g2  = (const float*)d_in[13];
  const float* bt2 = (const float*)d_in[14];
  const float* Wc  = (const float*)d_in[15];
  const float* bc  = (const float*)d_in[16];

  const int* src = ei;        // edge_index[0]
  const int* dst = ei + NE;   // edge_index[1]

  char* ws = (char*)d_ws;
  size_t off = 0;
  auto take = [&](size_t bytes) -> char* {
    char* p = ws + off;
    off = (off + bytes + 255) & ~(size_t)255;
    return p;
  };
  int* deg      = (int*)take((size_t)NN * 4);
  int* row_ptr  = (int*)take((size_t)(NN + 1) * 4);
  int* cursor   = (int*)take((size_t)NN * 4);
  int* col      = (int*)take((size_t)NE * 4);
  float* w1c    = (float*)take((size_t)336 * 256 * 4);
  float* w2s    = (float*)take((size_t)256 * 256 * 4);
  float* w3s    = (float*)take((size_t)128 * 128 * 4);
  float* bnacc  = (float*)take(512 * 4);
  float* A      = (float*)take((size_t)NN * 336 * 4);  // XC1 / h1 / h2raw / z3
  float* B      = (float*)take((size_t)NN * 256 * 4);  // h1raw / z2 / h2

  float* XC1   = A;  // [NN][336]: agg1 | pad2 | x | pad2
  float* h1raw = B;  // [NN][256]
  float* h1    = A;  // [NN][256]
  float* z2    = B;  // [NN][256] = h1 @ [Wl2^T | Wr2^T]
  float* h2raw = A;  // [NN][128]
  float* h2    = B;  // [NN][128]
  float* z3    = A;  // [NN][128] = h2 @ [Wl3^T | Wr3^T]

  float* logits = (float*)d_out;
  float* emb    = (float*)d_out + (size_t)NN * 2;

  // CSR build
  hipMemsetAsync(deg, 0, (size_t)NN * 4, stream);
  k_histo<<<(NE + 255) / 256, 256, 0, stream>>>(dst, deg);
  k_scan<<<1, 1024, 0, stream>>>(deg, row_ptr);
  hipMemsetAsync(cursor, 0, (size_t)NN * 4, stream);
  k_scatter<<<(NE + 255) / 256, 256, 0, stream>>>(src, dst, row_ptr, cursor, col);

  // weight packing
  k_pack_w<<<(2 * 168 * 256 + 255) / 256, 256, 0, stream>>>(Wl1, Wr1, w1c, 166, 168, 256);
  k_pack_w_n<<<(256 * 256 + 255) / 256, 256, 0, stream>>>(Wl2, Wr2, w2s, 256, 128);
  k_pack_w_n<<<(128 * 128 + 255) / 256, 256, 0, stream>>>(Wle, Wre, w3s, 128, 64);

  int agrid = (NN + 3) / 4;

  // ---- layer 1: XC1 = [agg(x) | x] (KC=336) @ w1c + b1 -> h1raw; BN+ReLU -> h1 ----
  k_pack_x<<<NN, 192, 0, stream>>>(x, XC1);
  k_agg<166, 4, false><<<agrid, 256, 0, stream>>>(x, 166, row_ptr, col, nullptr, 0, nullptr, XC1, 336);
  {
    dim3 g((NN + 63) / 64, 4);
    k_gemm_t<true><<<g, 256, 0, stream>>>(XC1, 336, w1c, b1, h1raw, 256);
  }
  hipMemsetAsync(bnacc, 0, 512 * 4, stream);
  k_bn_stats<256><<<256, 256, 0, stream>>>(h1raw, bnacc);
  k_bn_apply<256><<<(NN * 256 + 255) / 256, 256, 0, stream>>>(h1raw, bnacc, g1, bt1, h1);

  // ---- layer 2: z2 = h1 @ [Wl2^T|Wr2^T]; h2raw = agg(z2[:,:128]) + z2[:,128:] + b2 ----
  {
    dim3 g((NN + 63) / 64, 4);
    k_gemm_t<false><<<g, 256, 0, stream>>>(h1, 256, w2s, nullptr, z2, 256);
  }
  k_agg<128, 8, true><<<agrid, 256, 0, stream>>>(z2, 256, row_ptr, col, z2 + 128, 256, b2, h2raw, 128);
  hipMemsetAsync(bnacc, 0, 512 * 4, stream);
  k_bn_stats<128><<<256, 128, 0, stream>>>(h2raw, bnacc);
  k_bn_apply<128><<<(NN * 128 + 255) / 256, 256, 0, stream>>>(h2raw, bnacc, g2, bt2, h2);

  // ---- layer 3: z3 = h2 @ [Wl3^T|Wr3^T]; emb = agg(z3[:,:64]) + z3[:,64:] + be ----
  {
    dim3 g((NN + 63) / 64, 2);
    k_gemm_t<false><<<g, 256, 0, stream>>>(h2, 128, w3s, nullptr, z3, 128);
  }
  k_agg<64, 8, true><<<agrid, 256, 0, stream>>>(z3, 128, row_ptr, col, z3 + 64, 128, be, emb, 64);

  k_classifier<<<(NN + 255) / 256, 256, 0, stream>>>(emb, Wc, bc, logits);
}

// Round 5
// 525.770 us; speedup vs baseline: 64.0468x; 1.4393x over previous
//
#include <hip/hip_runtime.h>

#define NN 50000
#define NE 800000
static constexpr float BN_EPS = 1e-5f;

typedef __attribute__((ext_vector_type(8))) short bf16x8;
typedef __attribute__((ext_vector_type(4))) float f32x4;

__device__ inline unsigned short f2bf(float f) {
  unsigned int u = __float_as_uint(f);
  return (unsigned short)((u + 0x7FFFu + ((u >> 16) & 1u)) >> 16);
}
__device__ inline float bf2f(unsigned int h) {
  return __uint_as_float(h << 16);
}

// ---------------- CSR build ----------------
__global__ void k_histo(const int* __restrict__ dst, int* __restrict__ deg) {
  int e = blockIdx.x * 256 + threadIdx.x;
  if (e < NE) atomicAdd(&deg[dst[e]], 1);
}

__global__ void k_scan(const int* __restrict__ deg, int* __restrict__ row_ptr) {
  __shared__ int ts[1024];
  int t = threadIdx.x;
  const int PER = (NN + 1023) / 1024;  // 49
  int base = t * PER;
  int s = 0;
  for (int i = 0; i < PER; ++i) { int idx = base + i; if (idx < NN) s += deg[idx]; }
  ts[t] = s;
  __syncthreads();
  for (int off = 1; off < 1024; off <<= 1) {
    int v = 0;
    if (t >= off) v = ts[t - off];
    __syncthreads();
    if (t >= off) ts[t] += v;
    __syncthreads();
  }
  int run = (t == 0) ? 0 : ts[t - 1];
  for (int i = 0; i < PER; ++i) {
    int idx = base + i;
    if (idx < NN) { row_ptr[idx] = run; run += deg[idx]; }
  }
  if (t == 1023) row_ptr[NN] = run;
}

__global__ void k_scatter(const int* __restrict__ src, const int* __restrict__ dst,
                          const int* __restrict__ row_ptr, int* __restrict__ cursor,
                          int* __restrict__ col) {
  int e = blockIdx.x * 256 + threadIdx.x;
  if (e >= NE) return;
  int d = dst[e];
  int p = atomicAdd(&cursor[d], 1);
  col[row_ptr[d] + p] = src[e];
}

// ---------------- conversions / packing ----------------
__global__ void k_cvt_bf4(const float* __restrict__ in, unsigned short* __restrict__ out, int n4) {
  int i = blockIdx.x * 256 + threadIdx.x;
  if (i >= n4) return;
  float4 v = reinterpret_cast<const float4*>(in)[i];
  unsigned short o[4] = {f2bf(v.x), f2bf(v.y), f2bf(v.z), f2bf(v.w)};
  *reinterpret_cast<ulong1*>(out + 4 * (size_t)i) = *reinterpret_cast<ulong1*>(o);
}

// XC1 bf16 [NN][384]: cols 0..165 = agg (written by k_aggb), 166..191 zero,
// 192..357 = x, 358..383 zero
__global__ void k_pack_xb(const float* __restrict__ x, unsigned short* __restrict__ XC1) {
  int row = blockIdx.x;
  int t = threadIdx.x;
  if (t >= 218) return;
  int c = 166 + t;  // 166..383
  float v = (c >= 192 && c < 358) ? x[(size_t)row * 166 + (c - 192)] : 0.f;
  XC1[(size_t)row * 384 + c] = f2bf(v);
}

// w1c [256][384] bf16: k<166 -> Wl1, 192<=k<358 -> Wr1, else 0   (B^T form [N][K])
__global__ void k_pack_w1(const float* __restrict__ Wl, const float* __restrict__ Wr,
                          unsigned short* __restrict__ WC) {
  int idx = blockIdx.x * 256 + threadIdx.x;
  if (idx >= 256 * 384) return;
  int n = idx / 384, k = idx - n * 384;
  float v = 0.f;
  if (k < 166) v = Wl[(size_t)n * 166 + k];
  else if (k >= 192 && k < 358) v = Wr[(size_t)n * 166 + (k - 192)];
  WC[idx] = f2bf(v);
}

// [Wl ; Wr] stacked along N -> WC [2*Nh][K] bf16 (B^T form)
__global__ void k_pack_wn(const float* __restrict__ Wl, const float* __restrict__ Wr,
                          unsigned short* __restrict__ WC, int K, int Nh) {
  int idx = blockIdx.x * 256 + threadIdx.x;
  if (idx >= 2 * Nh * K) return;
  int n = idx / K, k = idx - n * K;
  WC[idx] = f2bf(n < Nh ? Wl[(size_t)n * K + k] : Wr[(size_t)(n - Nh) * K + k]);
}

// ---------------- bf16 mean aggregation (uint pairs, fp32 accumulate) ----------------
// LPN lanes per node; FUSE: out = mean + self + bias; OUTBF: bf16-pair out else float2 out
template <int D, int U, bool FUSE, bool OUTBF>
__global__ __launch_bounds__(256) void k_aggb(
    const unsigned int* __restrict__ feat, int fsu,
    const int* __restrict__ row_ptr, const int* __restrict__ col,
    const unsigned int* __restrict__ self, int ssu,
    const float* __restrict__ bias,
    void* __restrict__ outv, int osu) {
  constexpr int D2 = D / 2;
  constexpr int LPN = (D2 < 64) ? D2 : 64;
  constexpr int NPB = 256 / LPN;
  constexpr int C = (D2 + LPN - 1) / LPN;
  int node = blockIdx.x * NPB + threadIdx.x / LPN;
  if (node >= NN) return;
  int lane = threadIdx.x % LPN;
  int beg = row_ptr[node], end = row_ptr[node + 1];
  float ax[C], ay[C];
#pragma unroll
  for (int c = 0; c < C; ++c) { ax[c] = 0.f; ay[c] = 0.f; }

  int j = beg;
  for (; j + U <= end; j += U) {
    const unsigned int* fp[U];
#pragma unroll
    for (int u = 0; u < U; ++u) fp[u] = feat + (size_t)col[j + u] * fsu;
#pragma unroll
    for (int c = 0; c < C; ++c) {
      int p = lane + c * LPN;
      unsigned int t[U];
#pragma unroll
      for (int u = 0; u < U; ++u) t[u] = (p < D2) ? fp[u][p] : 0u;
#pragma unroll
      for (int u = 0; u < U; ++u) {
        ax[c] += bf2f(t[u] & 0xffffu);
        ay[c] += bf2f(t[u] >> 16);
      }
    }
  }
  for (; j < end; ++j) {
    const unsigned int* fr = feat + (size_t)col[j] * fsu;
#pragma unroll
    for (int c = 0; c < C; ++c) {
      int p = lane + c * LPN;
      if (p < D2) {
        unsigned int t = fr[p];
        ax[c] += bf2f(t & 0xffffu);
        ay[c] += bf2f(t >> 16);
      }
    }
  }
  float inv = 1.0f / fmaxf((float)(end - beg), 1.0f);
#pragma unroll
  for (int c = 0; c < C; ++c) {
    int p = lane + c * LPN;
    if (p < D2) {
      float vx = ax[c] * inv, vy = ay[c] * inv;
      if constexpr (FUSE) {
        unsigned int s = self[(size_t)node * ssu + p];
        vx += bf2f(s & 0xffffu) + bias[2 * p];
        vy += bf2f(s >> 16) + bias[2 * p + 1];
      }
      if constexpr (OUTBF) {
        unsigned int o = (unsigned int)f2bf(vx) | ((unsigned int)f2bf(vy) << 16);
        ((unsigned int*)outv)[(size_t)node * osu + p] = o;
      } else {
        float2 o{vx, vy};
        *reinterpret_cast<float2*>((float*)outv + (size_t)node * osu + 2 * p) = o;
      }
    }
  }
}

// ---------------- bf16 MFMA GEMM: out[M x Ntot](bf16) = A[M x KC] @ W[Ntot x KC]^T ----
// 128x128 tile, BK=64, 4 waves (each 64x64 = 4x4 frags of 16x16x32), XOR-swizzled LDS.
template <bool BIASED>
__global__ __launch_bounds__(256) void k_gemm_mfma(
    const unsigned short* __restrict__ A, int KC,
    const unsigned short* __restrict__ W,
    const float* __restrict__ bias,
    unsigned short* __restrict__ out, int Ntot) {
  __shared__ __align__(16) char lds[32768];
  char* lA = lds;
  char* lB = lds + 16384;
  int tid = threadIdx.x;
  int lane = tid & 63;
  int w = tid >> 6;
  int wr = w >> 1, wc = w & 1;
  int m0 = blockIdx.x * 128;
  int n0 = blockIdx.y * 128;

  f32x4 acc[4][4];
#pragma unroll
  for (int i = 0; i < 4; ++i)
#pragma unroll
    for (int j = 0; j < 4; ++j) acc[i][j] = f32x4{0.f, 0.f, 0.f, 0.f};

  for (int k0 = 0; k0 < KC; k0 += 64) {
    __syncthreads();
#pragma unroll
    for (int i = 0; i < 4; ++i) {
      int c = tid + i * 256;
      int row = c >> 3;            // 0..127
      int cb = (c & 7) << 4;       // byte col 0..112
      int sw = cb ^ ((row & 7) << 4);
      int gr = m0 + row;
      bf16x8 av = {0, 0, 0, 0, 0, 0, 0, 0};
      if (gr < NN)
        av = *reinterpret_cast<const bf16x8*>((const char*)A + ((size_t)gr * KC + k0) * 2 + cb);
      *reinterpret_cast<bf16x8*>(lA + row * 128 + sw) = av;
      bf16x8 wv = *reinterpret_cast<const bf16x8*>(
          (const char*)W + ((size_t)(n0 + row) * KC + k0) * 2 + cb);
      *reinterpret_cast<bf16x8*>(lB + row * 128 + sw) = wv;
    }
    __syncthreads();
#pragma unroll
    for (int ks = 0; ks < 2; ++ks) {
      bf16x8 af[4], bfr[4];
      int ac = ks * 64 + ((lane >> 4) << 4);
#pragma unroll
      for (int f = 0; f < 4; ++f) {
        int ar = wr * 64 + f * 16 + (lane & 15);
        af[f] = *reinterpret_cast<const bf16x8*>(lA + ar * 128 + (ac ^ ((ar & 7) << 4)));
        int br = wc * 64 + f * 16 + (lane & 15);
        bfr[f] = *reinterpret_cast<const bf16x8*>(lB + br * 128 + (ac ^ ((br & 7) << 4)));
      }
#pragma unroll
      for (int fm = 0; fm < 4; ++fm)
#pragma unroll
        for (int fn = 0; fn < 4; ++fn)
          acc[fm][fn] = __builtin_amdgcn_mfma_f32_16x16x32_bf16(af[fm], bfr[fn], acc[fm][fn], 0, 0, 0);
    }
  }

  int nbase = n0 + wc * 64 + (lane & 15);
  float bv[4] = {0.f, 0.f, 0.f, 0.f};
  if constexpr (BIASED) {
#pragma unroll
    for (int fn = 0; fn < 4; ++fn) bv[fn] = bias[nbase + fn * 16];
  }
#pragma unroll
  for (int fm = 0; fm < 4; ++fm) {
    int mbase = m0 + wr * 64 + fm * 16 + ((lane >> 4) << 2);
#pragma unroll
    for (int j = 0; j < 4; ++j) {
      int m = mbase + j;
      if (m < NN) {
#pragma unroll
        for (int fn = 0; fn < 4; ++fn)
          out[(size_t)m * Ntot + nbase + fn * 16] = f2bf(acc[fm][fn][j] + bv[fn]);
      }
    }
  }
}

// ---------------- BatchNorm ----------------
template <int N>
__global__ void k_bn_stats_b(const unsigned short* __restrict__ h, float* __restrict__ acc) {
  int c = threadIdx.x;
  int rows = (NN + gridDim.x - 1) / gridDim.x;
  int r0 = blockIdx.x * rows, r1 = min(r0 + rows, NN);
  float s = 0.f, s2 = 0.f;
  for (int r = r0; r < r1; ++r) {
    float v = bf2f((unsigned int)h[(size_t)r * N + c]);
    s += v; s2 += v * v;
  }
  atomicAdd(&acc[c], s);
  atomicAdd(&acc[N + c], s2);
}

template <int N>
__global__ void k_bn_stats_f(const float* __restrict__ h, float* __restrict__ acc) {
  int c = threadIdx.x;
  int rows = (NN + gridDim.x - 1) / gridDim.x;
  int r0 = blockIdx.x * rows, r1 = min(r0 + rows, NN);
  float s = 0.f, s2 = 0.f;
  for (int r = r0; r < r1; ++r) {
    float v = h[(size_t)r * N + c];
    s += v; s2 += v * v;
  }
  atomicAdd(&acc[c], s);
  atomicAdd(&acc[N + c], s2);
}

// pair-wise BN apply + ReLU; INF32: fp32 input else bf16-pair input; bf16-pair output
template <int N, bool INF32>
__global__ void k_bn_apply2(const void* __restrict__ hv, const float* __restrict__ acc,
                            const float* __restrict__ g, const float* __restrict__ b,
                            unsigned int* __restrict__ out) {
  constexpr int N2 = N / 2;
  int p = blockIdx.x * 256 + threadIdx.x;
  if (p >= NN * N2) return;
  int cp = p % N2;
  int c0 = 2 * cp, c1 = c0 + 1;
  float v0, v1;
  if constexpr (INF32) {
    float2 u = reinterpret_cast<const float2*>(hv)[p];
    v0 = u.x; v1 = u.y;
  } else {
    unsigned int u = reinterpret_cast<const unsigned int*>(hv)[p];
    v0 = bf2f(u & 0xffffu); v1 = bf2f(u >> 16);
  }
  float m0 = acc[c0] * (1.0f / NN);
  float m1 = acc[c1] * (1.0f / NN);
  float sc0 = g[c0] * rsqrtf(acc[N + c0] * (1.0f / NN) - m0 * m0 + BN_EPS);
  float sc1 = g[c1] * rsqrtf(acc[N + c1] * (1.0f / NN) - m1 * m1 + BN_EPS);
  float r0 = fmaxf((v0 - m0) * sc0 + b[c0], 0.f);
  float r1 = fmaxf((v1 - m1) * sc1 + b[c1], 0.f);
  out[p] = (unsigned int)f2bf(r0) | ((unsigned int)f2bf(r1) << 16);
}

// ---------------- classifier ----------------
__global__ void k_classifier(const float* __restrict__ emb, const float* __restrict__ Wc,
                             const float* __restrict__ bc, float* __restrict__ logits) {
  int row = blockIdx.x * 256 + threadIdx.x;
  if (row >= NN) return;
  const float* e = emb + (size_t)row * 64;
  float s0 = bc[0], s1 = bc[1];
#pragma unroll
  for (int k = 0; k < 64; ++k) { float v = e[k]; s0 += v * Wc[k]; s1 += v * Wc[64 + k]; }
  logits[row * 2 + 0] = s0;
  logits[row * 2 + 1] = s1;
}

extern "C" void kernel_launch(void* const* d_in, const int* in_sizes, int n_in,
                              void* d_out, int out_size, void* d_ws, size_t ws_size,
                              hipStream_t stream) {
  const float* x   = (const float*)d_in[0];
  const int* ei    = (const int*)d_in[1];
  const float* Wl1 = (const float*)d_in[2];
  const float* Wr1 = (const float*)d_in[3];
  const float* b1  = (const float*)d_in[4];
  const float* Wl2 = (const float*)d_in[5];
  const float* Wr2 = (const float*)d_in[6];
  const float* b2  = (const float*)d_in[7];
  const float* Wle = (const float*)d_in[8];
  const float* Wre = (const float*)d_in[9];
  const float* be  = (const float*)d_in[10];
  const float* g1  = (const float*)d_in[11];
  const float* bt1 = (const float*)d_in[12];
  const float* g2  = (const float*)d_in[13];
  const float* bt2 = (const float*)d_in[14];
  const float* Wc  = (const float*)d_in[15];
  const float* bc  = (const float*)d_in[16];

  const int* src = ei;
  const int* dst = ei + NE;

  char* ws = (char*)d_ws;
  size_t off = 0;
  auto take = [&](size_t bytes) -> char* {
    char* p = ws + off;
    off = (off + bytes + 255) & ~(size_t)255;
    return p;
  };
  int* deg      = (int*)take((size_t)NN * 4);
  int* row_ptr  = (int*)take((size_t)(NN + 1) * 4);
  int* cursor   = (int*)take((size_t)NN * 4);
  int* col      = (int*)take((size_t)NE * 4);
  unsigned short* w1c = (unsigned short*)take((size_t)256 * 384 * 2);
  unsigned short* w2s = (unsigned short*)take((size_t)256 * 256 * 2);
  unsigned short* w3s = (unsigned short*)take((size_t)128 * 128 * 2);
  float* bnacc  = (float*)take(512 * 4);
  unsigned short* xbf = (unsigned short*)take((size_t)NN * 166 * 2);
  char* P0 = take((size_t)NN * 384 * 2);  // XC1(bf) / h1(bf) / h2raw(f32,128) / z3(bf)
  char* P1 = take((size_t)NN * 256 * 2);  // h1raw(bf) / z2(bf) / h2(bf)

  unsigned short* XC1   = (unsigned short*)P0;  // [NN][384]
  unsigned short* h1raw = (unsigned short*)P1;  // [NN][256]
  unsigned short* h1    = (unsigned short*)P0;  // [NN][256]
  unsigned short* z2    = (unsigned short*)P1;  // [NN][256]
  float*          h2raw = (float*)P0;           // [NN][128]
  unsigned short* h2    = (unsigned short*)P1;  // [NN][128]
  unsigned short* z3    = (unsigned short*)P0;  // [NN][128]

  float* logits = (float*)d_out;
  float* emb    = (float*)d_out + (size_t)NN * 2;

  // CSR build
  hipMemsetAsync(deg, 0, (size_t)NN * 4, stream);
  k_histo<<<(NE + 255) / 256, 256, 0, stream>>>(dst, deg);
  k_scan<<<1, 1024, 0, stream>>>(deg, row_ptr);
  hipMemsetAsync(cursor, 0, (size_t)NN * 4, stream);
  k_scatter<<<(NE + 255) / 256, 256, 0, stream>>>(src, dst, row_ptr, cursor, col);

  // conversions + weight packing
  k_cvt_bf4<<<(NN * 166 / 4 + 255) / 256, 256, 0, stream>>>(x, xbf, NN * 166 / 4);
  k_pack_w1<<<(256 * 384 + 255) / 256, 256, 0, stream>>>(Wl1, Wr1, w1c);
  k_pack_wn<<<(256 * 256 + 255) / 256, 256, 0, stream>>>(Wl2, Wr2, w2s, 256, 128);
  k_pack_wn<<<(128 * 128 + 255) / 256, 256, 0, stream>>>(Wle, Wre, w3s, 128, 64);

  // ---- layer 1: XC1 = [agg(x) | x] bf16 (KC=384) @ w1c + b1 -> h1raw; BN+ReLU -> h1 ----
  k_pack_xb<<<NN, 224, 0, stream>>>(x, XC1);
  k_aggb<166, 4, false, true><<<(NN + 3) / 4, 256, 0, stream>>>(
      (const unsigned int*)xbf, 83, row_ptr, col, nullptr, 0, nullptr, XC1, 192);
  {
    dim3 g((NN + 127) / 128, 2);
    k_gemm_mfma<true><<<g, 256, 0, stream>>>(XC1, 384, w1c, b1, h1raw, 256);
  }
  hipMemsetAsync(bnacc, 0, 512 * 4, stream);
  k_bn_stats_b<256><<<256, 256, 0, stream>>>(h1raw, bnacc);
  k_bn_apply2<256, false><<<(NN * 128 + 255) / 256, 256, 0, stream>>>(
      h1raw, bnacc, g1, bt1, (unsigned int*)h1);

  // ---- layer 2: z2 = h1 @ [Wl2;Wr2]^T; h2raw = agg(z2[:,:128]) + z2[:,128:] + b2 ----
  {
    dim3 g((NN + 127) / 128, 2);
    k_gemm_mfma<false><<<g, 256, 0, stream>>>(h1, 256, w2s, nullptr, z2, 256);
  }
  k_aggb<128, 8, true, false><<<(NN + 3) / 4, 256, 0, stream>>>(
      (const unsigned int*)z2, 128, row_ptr, col, (const unsigned int*)z2 + 64, 128, b2, h2raw, 128);
  hipMemsetAsync(bnacc, 0, 512 * 4, stream);
  k_bn_stats_f<128><<<256, 128, 0, stream>>>(h2raw, bnacc);
  k_bn_apply2<128, true><<<(NN * 64 + 255) / 256, 256, 0, stream>>>(
      h2raw, bnacc, g2, bt2, (unsigned int*)h2);

  // ---- layer 3: z3 = h2 @ [Wle;Wre]^T; emb = agg(z3[:,:64]) + z3[:,64:] + be ----
  {
    dim3 g((NN + 127) / 128, 1);
    k_gemm_mfma<false><<<g, 256, 0, stream>>>(h2, 128, w3s, nullptr, z3, 128);
  }
  k_aggb<64, 8, true, false><<<(NN + 7) / 8, 256, 0, stream>>>(
      (const unsigned int*)z3, 64, row_ptr, col, (const unsigned int*)z3 + 32, 64, be, emb, 64);

  k_classifier<<<(NN + 255) / 256, 256, 0, stream>>>(emb, Wc, bc, logits);
}

// Round 6
// 444.594 us; speedup vs baseline: 75.7408x; 1.1826x over previous
//
#include <hip/hip_runtime.h>

#define NN 50000
#define NE 800000
#define SCAN_B ((NN + 255) / 256)  // 196
static constexpr float BN_EPS = 1e-5f;

typedef __attribute__((ext_vector_type(8))) short bf16x8;
typedef __attribute__((ext_vector_type(4))) float f32x4;

__device__ inline unsigned short f2bf(float f) {
  unsigned int u = __float_as_uint(f);
  return (unsigned short)((u + 0x7FFFu + ((u >> 16) & 1u)) >> 16);
}
__device__ inline float bf2f(unsigned int h) {
  return __uint_as_float(h << 16);
}

// ---------------- CSR build ----------------
__global__ void k_histo(const int* __restrict__ dst, int* __restrict__ deg) {
  int e = blockIdx.x * 256 + threadIdx.x;
  if (e < NE) atomicAdd(&deg[dst[e]], 1);
}

// pass 1: per-block scan (256 elems), write local exclusive prefix + block sum
__global__ void k_scan1(const int* __restrict__ deg, int* __restrict__ row_ptr,
                        int* __restrict__ bsum) {
  __shared__ int ts[256];
  int t = threadIdx.x;
  int i = blockIdx.x * 256 + t;
  int v = (i < NN) ? deg[i] : 0;
  ts[t] = v;
  __syncthreads();
#pragma unroll
  for (int off = 1; off < 256; off <<= 1) {
    int u = (t >= off) ? ts[t - off] : 0;
    __syncthreads();
    ts[t] += u;
    __syncthreads();
  }
  if (i < NN) row_ptr[i] = ts[t] - v;
  if (t == 255) bsum[blockIdx.x] = ts[255];
}

// pass 2: single block scans the block sums -> exclusive offsets
__global__ void k_scan2(int* __restrict__ bsum, int* __restrict__ boff) {
  __shared__ int ts[256];
  int t = threadIdx.x;
  int v = (t < SCAN_B) ? bsum[t] : 0;
  ts[t] = v;
  __syncthreads();
#pragma unroll
  for (int off = 1; off < 256; off <<= 1) {
    int u = (t >= off) ? ts[t - off] : 0;
    __syncthreads();
    ts[t] += u;
    __syncthreads();
  }
  boff[t] = ts[t] - v;
}

// pass 3: add block offsets; row_ptr[NN] = NE (all edges counted)
__global__ void k_scan3(int* __restrict__ row_ptr, const int* __restrict__ boff) {
  int i = blockIdx.x * 256 + threadIdx.x;
  if (i < NN) row_ptr[i] += boff[blockIdx.x];
  if (i == 0) row_ptr[NN] = NE;
}

__global__ void k_scatter(const int* __restrict__ src, const int* __restrict__ dst,
                          const int* __restrict__ row_ptr, int* __restrict__ cursor,
                          int* __restrict__ col) {
  int e = blockIdx.x * 256 + threadIdx.x;
  if (e >= NE) return;
  int d = dst[e];
  int p = atomicAdd(&cursor[d], 1);
  col[row_ptr[d] + p] = src[e];
}

// ---------------- conversions / packing ----------------
__global__ void k_cvt_bf4(const float* __restrict__ in, unsigned short* __restrict__ out, int n4) {
  int i = blockIdx.x * 256 + threadIdx.x;
  if (i >= n4) return;
  float4 v = reinterpret_cast<const float4*>(in)[i];
  unsigned short o[4] = {f2bf(v.x), f2bf(v.y), f2bf(v.z), f2bf(v.w)};
  *reinterpret_cast<ulong1*>(out + 4 * (size_t)i) = *reinterpret_cast<ulong1*>(o);
}

// XC1 bf16 [NN][384]: cols 0..165 = agg (written by k_aggb), 166..191 zero,
// 192..357 = x, 358..383 zero
__global__ void k_pack_xb(const float* __restrict__ x, unsigned short* __restrict__ XC1) {
  int row = blockIdx.x;
  int t = threadIdx.x;
  if (t >= 218) return;
  int c = 166 + t;  // 166..383
  float v = (c >= 192 && c < 358) ? x[(size_t)row * 166 + (c - 192)] : 0.f;
  XC1[(size_t)row * 384 + c] = f2bf(v);
}

// w1c [256][384] bf16: k<166 -> Wl1, 192<=k<358 -> Wr1, else 0   (B^T form [N][K])
__global__ void k_pack_w1(const float* __restrict__ Wl, const float* __restrict__ Wr,
                          unsigned short* __restrict__ WC) {
  int idx = blockIdx.x * 256 + threadIdx.x;
  if (idx >= 256 * 384) return;
  int n = idx / 384, k = idx - n * 384;
  float v = 0.f;
  if (k < 166) v = Wl[(size_t)n * 166 + k];
  else if (k >= 192 && k < 358) v = Wr[(size_t)n * 166 + (k - 192)];
  WC[idx] = f2bf(v);
}

// [Wl ; Wr] stacked along N -> WC [2*Nh][K] bf16 (B^T form)
__global__ void k_pack_wn(const float* __restrict__ Wl, const float* __restrict__ Wr,
                          unsigned short* __restrict__ WC, int K, int Nh) {
  int idx = blockIdx.x * 256 + threadIdx.x;
  if (idx >= 2 * Nh * K) return;
  int n = idx / K, k = idx - n * K;
  WC[idx] = f2bf(n < Nh ? Wl[(size_t)n * K + k] : Wr[(size_t)(n - Nh) * K + k]);
}

// ---------------- bf16 mean aggregation (uint pairs, fp32 accumulate) ----------------
template <int D, int U, bool FUSE, bool OUTBF>
__global__ __launch_bounds__(256) void k_aggb(
    const unsigned int* __restrict__ feat, int fsu,
    const int* __restrict__ row_ptr, const int* __restrict__ col,
    const unsigned int* __restrict__ self, int ssu,
    const float* __restrict__ bias,
    void* __restrict__ outv, int osu) {
  constexpr int D2 = D / 2;
  constexpr int LPN = (D2 < 64) ? D2 : 64;
  constexpr int NPB = 256 / LPN;
  constexpr int C = (D2 + LPN - 1) / LPN;
  int node = blockIdx.x * NPB + threadIdx.x / LPN;
  if (node >= NN) return;
  int lane = threadIdx.x % LPN;
  int beg = row_ptr[node], end = row_ptr[node + 1];
  float ax[C], ay[C];
#pragma unroll
  for (int c = 0; c < C; ++c) { ax[c] = 0.f; ay[c] = 0.f; }

  int j = beg;
  for (; j + U <= end; j += U) {
    const unsigned int* fp[U];
#pragma unroll
    for (int u = 0; u < U; ++u) fp[u] = feat + (size_t)col[j + u] * fsu;
#pragma unroll
    for (int c = 0; c < C; ++c) {
      int p = lane + c * LPN;
      unsigned int t[U];
#pragma unroll
      for (int u = 0; u < U; ++u) t[u] = (p < D2) ? fp[u][p] : 0u;
#pragma unroll
      for (int u = 0; u < U; ++u) {
        ax[c] += bf2f(t[u] & 0xffffu);
        ay[c] += bf2f(t[u] >> 16);
      }
    }
  }
  for (; j < end; ++j) {
    const unsigned int* fr = feat + (size_t)col[j] * fsu;
#pragma unroll
    for (int c = 0; c < C; ++c) {
      int p = lane + c * LPN;
      if (p < D2) {
        unsigned int t = fr[p];
        ax[c] += bf2f(t & 0xffffu);
        ay[c] += bf2f(t >> 16);
      }
    }
  }
  float inv = 1.0f / fmaxf((float)(end - beg), 1.0f);
#pragma unroll
  for (int c = 0; c < C; ++c) {
    int p = lane + c * LPN;
    if (p < D2) {
      float vx = ax[c] * inv, vy = ay[c] * inv;
      if constexpr (FUSE) {
        unsigned int s = self[(size_t)node * ssu + p];
        vx += bf2f(s & 0xffffu) + bias[2 * p];
        vy += bf2f(s >> 16) + bias[2 * p + 1];
      }
      if constexpr (OUTBF) {
        unsigned int o = (unsigned int)f2bf(vx) | ((unsigned int)f2bf(vy) << 16);
        ((unsigned int*)outv)[(size_t)node * osu + p] = o;
      } else {
        float2 o{vx, vy};
        *reinterpret_cast<float2*>((float*)outv + (size_t)node * osu + 2 * p) = o;
      }
    }
  }
}

// ---------------- bf16 MFMA GEMM: out[M x Ntot](bf16) = A[M x KC] @ W[Ntot x KC]^T ----
template <bool BIASED>
__global__ __launch_bounds__(256) void k_gemm_mfma(
    const unsigned short* __restrict__ A, int KC,
    const unsigned short* __restrict__ W,
    const float* __restrict__ bias,
    unsigned short* __restrict__ out, int Ntot) {
  __shared__ __align__(16) char lds[32768];
  char* lA = lds;
  char* lB = lds + 16384;
  int tid = threadIdx.x;
  int lane = tid & 63;
  int w = tid >> 6;
  int wr = w >> 1, wc = w & 1;
  int m0 = blockIdx.x * 128;
  int n0 = blockIdx.y * 128;

  f32x4 acc[4][4];
#pragma unroll
  for (int i = 0; i < 4; ++i)
#pragma unroll
    for (int j = 0; j < 4; ++j) acc[i][j] = f32x4{0.f, 0.f, 0.f, 0.f};

  for (int k0 = 0; k0 < KC; k0 += 64) {
    __syncthreads();
#pragma unroll
    for (int i = 0; i < 4; ++i) {
      int c = tid + i * 256;
      int row = c >> 3;            // 0..127
      int cb = (c & 7) << 4;       // byte col 0..112
      int sw = cb ^ ((row & 7) << 4);
      int gr = m0 + row;
      bf16x8 av = {0, 0, 0, 0, 0, 0, 0, 0};
      if (gr < NN)
        av = *reinterpret_cast<const bf16x8*>((const char*)A + ((size_t)gr * KC + k0) * 2 + cb);
      *reinterpret_cast<bf16x8*>(lA + row * 128 + sw) = av;
      bf16x8 wv = *reinterpret_cast<const bf16x8*>(
          (const char*)W + ((size_t)(n0 + row) * KC + k0) * 2 + cb);
      *reinterpret_cast<bf16x8*>(lB + row * 128 + sw) = wv;
    }
    __syncthreads();
#pragma unroll
    for (int ks = 0; ks < 2; ++ks) {
      bf16x8 af[4], bfr[4];
      int ac = ks * 64 + ((lane >> 4) << 4);
#pragma unroll
      for (int f = 0; f < 4; ++f) {
        int ar = wr * 64 + f * 16 + (lane & 15);
        af[f] = *reinterpret_cast<const bf16x8*>(lA + ar * 128 + (ac ^ ((ar & 7) << 4)));
        int br = wc * 64 + f * 16 + (lane & 15);
        bfr[f] = *reinterpret_cast<const bf16x8*>(lB + br * 128 + (ac ^ ((br & 7) << 4)));
      }
#pragma unroll
      for (int fm = 0; fm < 4; ++fm)
#pragma unroll
        for (int fn = 0; fn < 4; ++fn)
          acc[fm][fn] = __builtin_amdgcn_mfma_f32_16x16x32_bf16(af[fm], bfr[fn], acc[fm][fn], 0, 0, 0);
    }
  }

  int nbase = n0 + wc * 64 + (lane & 15);
  float bv[4] = {0.f, 0.f, 0.f, 0.f};
  if constexpr (BIASED) {
#pragma unroll
    for (int fn = 0; fn < 4; ++fn) bv[fn] = bias[nbase + fn * 16];
  }
#pragma unroll
  for (int fm = 0; fm < 4; ++fm) {
    int mbase = m0 + wr * 64 + fm * 16 + ((lane >> 4) << 2);
#pragma unroll
    for (int j = 0; j < 4; ++j) {
      int m = mbase + j;
      if (m < NN) {
#pragma unroll
        for (int fn = 0; fn < 4; ++fn)
          out[(size_t)m * Ntot + nbase + fn * 16] = f2bf(acc[fm][fn][j] + bv[fn]);
      }
    }
  }
}

// ---------------- BatchNorm ----------------
template <int N>
__global__ void k_bn_stats_b(const unsigned short* __restrict__ h, float* __restrict__ acc) {
  int c = threadIdx.x;
  int rows = (NN + gridDim.x - 1) / gridDim.x;
  int r0 = blockIdx.x * rows, r1 = min(r0 + rows, NN);
  float s = 0.f, s2 = 0.f;
  for (int r = r0; r < r1; ++r) {
    float v = bf2f((unsigned int)h[(size_t)r * N + c]);
    s += v; s2 += v * v;
  }
  atomicAdd(&acc[c], s);
  atomicAdd(&acc[N + c], s2);
}

template <int N>
__global__ void k_bn_stats_f(const float* __restrict__ h, float* __restrict__ acc) {
  int c = threadIdx.x;
  int rows = (NN + gridDim.x - 1) / gridDim.x;
  int r0 = blockIdx.x * rows, r1 = min(r0 + rows, NN);
  float s = 0.f, s2 = 0.f;
  for (int r = r0; r < r1; ++r) {
    float v = h[(size_t)r * N + c];
    s += v; s2 += v * v;
  }
  atomicAdd(&acc[c], s);
  atomicAdd(&acc[N + c], s2);
}

// pair-wise BN apply + ReLU
template <int N, bool INF32>
__global__ void k_bn_apply2(const void* __restrict__ hv, const float* __restrict__ acc,
                            const float* __restrict__ g, const float* __restrict__ b,
                            unsigned int* __restrict__ out) {
  constexpr int N2 = N / 2;
  int p = blockIdx.x * 256 + threadIdx.x;
  if (p >= NN * N2) return;
  int cp = p % N2;
  int c0 = 2 * cp, c1 = c0 + 1;
  float v0, v1;
  if constexpr (INF32) {
    float2 u = reinterpret_cast<const float2*>(hv)[p];
    v0 = u.x; v1 = u.y;
  } else {
    unsigned int u = reinterpret_cast<const unsigned int*>(hv)[p];
    v0 = bf2f(u & 0xffffu); v1 = bf2f(u >> 16);
  }
  float m0 = acc[c0] * (1.0f / NN);
  float m1 = acc[c1] * (1.0f / NN);
  float sc0 = g[c0] * rsqrtf(acc[N + c0] * (1.0f / NN) - m0 * m0 + BN_EPS);
  float sc1 = g[c1] * rsqrtf(acc[N + c1] * (1.0f / NN) - m1 * m1 + BN_EPS);
  float r0 = fmaxf((v0 - m0) * sc0 + b[c0], 0.f);
  float r1 = fmaxf((v1 - m1) * sc1 + b[c1], 0.f);
  out[p] = (unsigned int)f2bf(r0) | ((unsigned int)f2bf(r1) << 16);
}

// ---------------- classifier ----------------
__global__ void k_classifier(const float* __restrict__ emb, const float* __restrict__ Wc,
                             const float* __restrict__ bc, float* __restrict__ logits) {
  int row = blockIdx.x * 256 + threadIdx.x;
  if (row >= NN) return;
  const float* e = emb + (size_t)row * 64;
  float s0 = bc[0], s1 = bc[1];
#pragma unroll
  for (int k = 0; k < 64; ++k) { float v = e[k]; s0 += v * Wc[k]; s1 += v * Wc[64 + k]; }
  logits[row * 2 + 0] = s0;
  logits[row * 2 + 1] = s1;
}

extern "C" void kernel_launch(void* const* d_in, const int* in_sizes, int n_in,
                              void* d_out, int out_size, void* d_ws, size_t ws_size,
                              hipStream_t stream) {
  const float* x   = (const float*)d_in[0];
  const int* ei    = (const int*)d_in[1];
  const float* Wl1 = (const float*)d_in[2];
  const float* Wr1 = (const float*)d_in[3];
  const float* b1  = (const float*)d_in[4];
  const float* Wl2 = (const float*)d_in[5];
  const float* Wr2 = (const float*)d_in[6];
  const float* b2  = (const float*)d_in[7];
  const float* Wle = (const float*)d_in[8];
  const float* Wre = (const float*)d_in[9];
  const float* be  = (const float*)d_in[10];
  const float* g1  = (const float*)d_in[11];
  const float* bt1 = (const float*)d_in[12];
  const float* g2  = (const float*)d_in[13];
  const float* bt2 = (const float*)d_in[14];
  const float* Wc  = (const float*)d_in[15];
  const float* bc  = (const float*)d_in[16];

  const int* src = ei;
  const int* dst = ei + NE;

  char* ws = (char*)d_ws;
  size_t off = 0;
  auto take = [&](size_t bytes) -> char* {
    char* p = ws + off;
    off = (off + bytes + 255) & ~(size_t)255;
    return p;
  };
  int* deg      = (int*)take((size_t)NN * 4);
  int* row_ptr  = (int*)take((size_t)(NN + 1) * 4);
  int* cursor   = (int*)take((size_t)NN * 4);
  int* bsum     = (int*)take(256 * 4);
  int* boff     = (int*)take(256 * 4);
  int* col      = (int*)take((size_t)NE * 4);
  unsigned short* w1c = (unsigned short*)take((size_t)256 * 384 * 2);
  unsigned short* w2s = (unsigned short*)take((size_t)256 * 256 * 2);
  unsigned short* w3s = (unsigned short*)take((size_t)128 * 128 * 2);
  float* bnacc  = (float*)take(512 * 4);
  unsigned short* xbf = (unsigned short*)take((size_t)NN * 166 * 2);
  char* P0 = take((size_t)NN * 384 * 2);
  char* P1 = take((size_t)NN * 256 * 2);

  unsigned short* XC1   = (unsigned short*)P0;  // [NN][384]
  unsigned short* h1raw = (unsigned short*)P1;  // [NN][256]
  unsigned short* h1    = (unsigned short*)P0;  // [NN][256]
  unsigned short* z2    = (unsigned short*)P1;  // [NN][256]
  float*          h2raw = (float*)P0;           // [NN][128]
  unsigned short* h2    = (unsigned short*)P1;  // [NN][128]
  unsigned short* z3    = (unsigned short*)P0;  // [NN][128]

  float* logits = (float*)d_out;
  float* emb    = (float*)d_out + (size_t)NN * 2;

  // CSR build (parallel scan)
  hipMemsetAsync(deg, 0, (size_t)NN * 4, stream);
  k_histo<<<(NE + 255) / 256, 256, 0, stream>>>(dst, deg);
  k_scan1<<<SCAN_B, 256, 0, stream>>>(deg, row_ptr, bsum);
  k_scan2<<<1, 256, 0, stream>>>(bsum, boff);
  k_scan3<<<SCAN_B, 256, 0, stream>>>(row_ptr, boff);
  hipMemsetAsync(cursor, 0, (size_t)NN * 4, stream);
  k_scatter<<<(NE + 255) / 256, 256, 0, stream>>>(src, dst, row_ptr, cursor, col);

  // conversions + weight packing
  k_cvt_bf4<<<(NN * 166 / 4 + 255) / 256, 256, 0, stream>>>(x, xbf, NN * 166 / 4);
  k_pack_w1<<<(256 * 384 + 255) / 256, 256, 0, stream>>>(Wl1, Wr1, w1c);
  k_pack_wn<<<(256 * 256 + 255) / 256, 256, 0, stream>>>(Wl2, Wr2, w2s, 256, 128);
  k_pack_wn<<<(128 * 128 + 255) / 256, 256, 0, stream>>>(Wle, Wre, w3s, 128, 64);

  // ---- layer 1 ----
  k_pack_xb<<<NN, 224, 0, stream>>>(x, XC1);
  k_aggb<166, 4, false, true><<<(NN + 3) / 4, 256, 0, stream>>>(
      (const unsigned int*)xbf, 83, row_ptr, col, nullptr, 0, nullptr, XC1, 192);
  {
    dim3 g((NN + 127) / 128, 2);
    k_gemm_mfma<true><<<g, 256, 0, stream>>>(XC1, 384, w1c, b1, h1raw, 256);
  }
  hipMemsetAsync(bnacc, 0, 512 * 4, stream);
  k_bn_stats_b<256><<<256, 256, 0, stream>>>(h1raw, bnacc);
  k_bn_apply2<256, false><<<(NN * 128 + 255) / 256, 256, 0, stream>>>(
      h1raw, bnacc, g1, bt1, (unsigned int*)h1);

  // ---- layer 2 ----
  {
    dim3 g((NN + 127) / 128, 2);
    k_gemm_mfma<false><<<g, 256, 0, stream>>>(h1, 256, w2s, nullptr, z2, 256);
  }
  k_aggb<128, 8, true, false><<<(NN + 3) / 4, 256, 0, stream>>>(
      (const unsigned int*)z2, 128, row_ptr, col, (const unsigned int*)z2 + 64, 128, b2, h2raw, 128);
  hipMemsetAsync(bnacc, 0, 512 * 4, stream);
  k_bn_stats_f<128><<<256, 128, 0, stream>>>(h2raw, bnacc);
  k_bn_apply2<128, true><<<(NN * 64 + 255) / 256, 256, 0, stream>>>(
      h2raw, bnacc, g2, bt2, (unsigned int*)h2);

  // ---- layer 3 ----
  {
    dim3 g((NN + 127) / 128, 1);
    k_gemm_mfma<false><<<g, 256, 0, stream>>>(h2, 128, w3s, nullptr, z3, 128);
  }
  k_aggb<64, 8, true, false><<<(NN + 7) / 8, 256, 0, stream>>>(
      (const unsigned int*)z3, 64, row_ptr, col, (const unsigned int*)z3 + 32, 64, be, emb, 64);

  k_classifier<<<(NN + 255) / 256, 256, 0, stream>>>(emb, Wc, bc, logits);
}

// Round 7
// 353.544 us; speedup vs baseline: 95.2467x; 1.2575x over previous
//
#include <hip/hip_runtime.h>

#define NN 50000
#define NE 800000
#define NB 256
#define BNODES ((NN + NB - 1) / NB)  // 196 nodes per bucket
static constexpr float BN_EPS = 1e-5f;

typedef __attribute__((ext_vector_type(8))) short bf16x8;
typedef __attribute__((ext_vector_type(4))) float f32x4;

__device__ inline unsigned short f2bf(float f) {
  unsigned int u = __float_as_uint(f);
  return (unsigned short)((u + 0x7FFFu + ((u >> 16) & 1u)) >> 16);
}
__device__ inline float bf2f(unsigned int h) {
  return __uint_as_float(h << 16);
}

// ================= CSR build: bucketed two-phase =================
// A1: bucket histogram (LDS-privatized)
__global__ void k_bhisto(const int* __restrict__ dst, int* __restrict__ bsize) {
  __shared__ int cnt[NB];
  int t = threadIdx.x;
  cnt[t] = 0;
  __syncthreads();
  int e0 = blockIdx.x * 8192 + t;
#pragma unroll
  for (int i = 0; i < 32; ++i) {
    int e = e0 + i * 256;
    if (e < NE) atomicAdd(&cnt[dst[e] / BNODES], 1);
  }
  __syncthreads();
  if (cnt[t]) atomicAdd(&bsize[t], cnt[t]);
}

// A2: scan bucket sizes -> bases + cursors; also row_ptr[NN]=NE
__global__ void k_bscan(const int* __restrict__ bsize, int* __restrict__ bbase,
                        int* __restrict__ bcur, int* __restrict__ row_ptr) {
  __shared__ int ts[NB];
  int t = threadIdx.x;
  int v = bsize[t];
  ts[t] = v;
  __syncthreads();
#pragma unroll
  for (int off = 1; off < NB; off <<= 1) {
    int u = (t >= off) ? ts[t - off] : 0;
    __syncthreads();
    ts[t] += u;
    __syncthreads();
  }
  bbase[t] = ts[t] - v;
  bcur[t] = ts[t] - v;
  if (t == NB - 1) { bbase[NB] = ts[t]; row_ptr[NN] = NE; }
}

// A3: partition edges into bucket-contiguous (src,dst) pairs
__global__ void k_bpart(const int* __restrict__ src, const int* __restrict__ dst,
                        int* __restrict__ bcur, uint2* __restrict__ pairs) {
  __shared__ int cnt[NB], lbase[NB], lcur[NB];
  int t = threadIdx.x;
  cnt[t] = 0;
  __syncthreads();
  int e0 = blockIdx.x * 8192 + t;
#pragma unroll
  for (int i = 0; i < 32; ++i) {
    int e = e0 + i * 256;
    if (e < NE) atomicAdd(&cnt[dst[e] / BNODES], 1);
  }
  __syncthreads();
  lbase[t] = cnt[t] ? atomicAdd(&bcur[t], cnt[t]) : 0;
  lcur[t] = 0;
  __syncthreads();
#pragma unroll
  for (int i = 0; i < 32; ++i) {
    int e = e0 + i * 256;
    if (e < NE) {
      int d = dst[e];
      int b = d / BNODES;
      int p = atomicAdd(&lcur[b], 1);
      pairs[(size_t)lbase[b] + p] = uint2{(unsigned)src[e], (unsigned)d};
    }
  }
}

// B: per-bucket: degree count -> local scan -> row_ptr + col scatter (L2-local window)
__global__ void k_bscatter(const uint2* __restrict__ pairs, const int* __restrict__ bbase,
                           int* __restrict__ row_ptr, int* __restrict__ col) {
  __shared__ int dcnt[NB], ts[NB], doff[NB], dcur[NB];
  int t = threadIdx.x;
  int b = blockIdx.x;
  int n0 = b * BNODES;
  int ncnt = min(NN - n0, BNODES);
  int e0 = bbase[b], e1 = bbase[b + 1];
  dcnt[t] = 0;
  __syncthreads();
  for (int e = e0 + t; e < e1; e += 256) atomicAdd(&dcnt[pairs[e].y - n0], 1);
  __syncthreads();
  ts[t] = dcnt[t];
  __syncthreads();
#pragma unroll
  for (int off = 1; off < NB; off <<= 1) {
    int u = (t >= off) ? ts[t - off] : 0;
    __syncthreads();
    ts[t] += u;
    __syncthreads();
  }
  doff[t] = ts[t] - dcnt[t];
  dcur[t] = 0;
  if (t < ncnt) row_ptr[n0 + t] = e0 + doff[t];
  __syncthreads();
  for (int e = e0 + t; e < e1; e += 256) {
    uint2 pr = pairs[e];
    int ld = pr.y - n0;
    int p = atomicAdd(&dcur[ld], 1);
    col[e0 + doff[ld] + p] = (int)pr.x;
  }
}

// ================= conversions / packing =================
__global__ void k_cvt_bf4(const float* __restrict__ in, unsigned short* __restrict__ out, int n4) {
  int i = blockIdx.x * 256 + threadIdx.x;
  if (i >= n4) return;
  float4 v = reinterpret_cast<const float4*>(in)[i];
  unsigned short o[4] = {f2bf(v.x), f2bf(v.y), f2bf(v.z), f2bf(v.w)};
  *reinterpret_cast<ulong1*>(out + 4 * (size_t)i) = *reinterpret_cast<ulong1*>(o);
}

// XC1 bf16 [NN][384]: 0..165 = agg (k_aggb), 166..191 zero, 192..357 = x, 358..383 zero
__global__ void k_pack_xb(const float* __restrict__ x, unsigned short* __restrict__ XC1) {
  int row = blockIdx.x;
  int t = threadIdx.x;
  if (t >= 218) return;
  int c = 166 + t;
  float v = (c >= 192 && c < 358) ? x[(size_t)row * 166 + (c - 192)] : 0.f;
  XC1[(size_t)row * 384 + c] = f2bf(v);
}

// w1c [256][384] bf16: k<166 -> Wl1, 192<=k<358 -> Wr1, else 0  (B^T form [N][K])
__global__ void k_pack_w1(const float* __restrict__ Wl, const float* __restrict__ Wr,
                          unsigned short* __restrict__ WC) {
  int idx = blockIdx.x * 256 + threadIdx.x;
  if (idx >= 256 * 384) return;
  int n = idx / 384, k = idx - n * 384;
  float v = 0.f;
  if (k < 166) v = Wl[(size_t)n * 166 + k];
  else if (k >= 192 && k < 358) v = Wr[(size_t)n * 166 + (k - 192)];
  WC[idx] = f2bf(v);
}

// [Wl ; Wr] stacked along N -> WC [2*Nh][K] bf16 (B^T form)
__global__ void k_pack_wn(const float* __restrict__ Wl, const float* __restrict__ Wr,
                          unsigned short* __restrict__ WC, int K, int Nh) {
  int idx = blockIdx.x * 256 + threadIdx.x;
  if (idx >= 2 * Nh * K) return;
  int n = idx / K, k = idx - n * K;
  WC[idx] = f2bf(n < Nh ? Wl[(size_t)n * K + k] : Wr[(size_t)(n - Nh) * K + k]);
}

// ================= bf16 mean aggregation =================
template <int D, int U, bool FUSE, bool OUTBF>
__global__ __launch_bounds__(256) void k_aggb(
    const unsigned int* __restrict__ feat, int fsu,
    const int* __restrict__ row_ptr, const int* __restrict__ col,
    const unsigned int* __restrict__ self, int ssu,
    const float* __restrict__ bias,
    void* __restrict__ outv, int osu) {
  constexpr int D2 = D / 2;
  constexpr int LPN = (D2 < 64) ? D2 : 64;
  constexpr int NPB = 256 / LPN;
  constexpr int C = (D2 + LPN - 1) / LPN;
  int node = blockIdx.x * NPB + threadIdx.x / LPN;
  if (node >= NN) return;
  int lane = threadIdx.x % LPN;
  int beg = row_ptr[node], end = row_ptr[node + 1];
  float ax[C], ay[C];
#pragma unroll
  for (int c = 0; c < C; ++c) { ax[c] = 0.f; ay[c] = 0.f; }

  int j = beg;
  for (; j + U <= end; j += U) {
    const unsigned int* fp[U];
#pragma unroll
    for (int u = 0; u < U; ++u) fp[u] = feat + (size_t)col[j + u] * fsu;
#pragma unroll
    for (int c = 0; c < C; ++c) {
      int p = lane + c * LPN;
      unsigned int t[U];
#pragma unroll
      for (int u = 0; u < U; ++u) t[u] = (p < D2) ? fp[u][p] : 0u;
#pragma unroll
      for (int u = 0; u < U; ++u) {
        ax[c] += bf2f(t[u] & 0xffffu);
        ay[c] += bf2f(t[u] >> 16);
      }
    }
  }
  for (; j < end; ++j) {
    const unsigned int* fr = feat + (size_t)col[j] * fsu;
#pragma unroll
    for (int c = 0; c < C; ++c) {
      int p = lane + c * LPN;
      if (p < D2) {
        unsigned int t = fr[p];
        ax[c] += bf2f(t & 0xffffu);
        ay[c] += bf2f(t >> 16);
      }
    }
  }
  float inv = 1.0f / fmaxf((float)(end - beg), 1.0f);
#pragma unroll
  for (int c = 0; c < C; ++c) {
    int p = lane + c * LPN;
    if (p < D2) {
      float vx = ax[c] * inv, vy = ay[c] * inv;
      if constexpr (FUSE) {
        unsigned int s = self[(size_t)node * ssu + p];
        vx += bf2f(s & 0xffffu) + bias[2 * p];
        vy += bf2f(s >> 16) + bias[2 * p + 1];
      }
      if constexpr (OUTBF) {
        unsigned int o = (unsigned int)f2bf(vx) | ((unsigned int)f2bf(vy) << 16);
        ((unsigned int*)outv)[(size_t)node * osu + p] = o;
      } else {
        float2 o{vx, vy};
        *reinterpret_cast<float2*>((float*)outv + (size_t)node * osu + 2 * p) = o;
      }
    }
  }
}

// ================= bf16 MFMA GEMM (+ optional fused BN stats) =================
template <bool BIASED, bool STATS>
__global__ __launch_bounds__(256) void k_gemm_mfma(
    const unsigned short* __restrict__ A, int KC,
    const unsigned short* __restrict__ W,
    const float* __restrict__ bias,
    unsigned short* __restrict__ out, int Ntot,
    float* __restrict__ statacc) {
  __shared__ __align__(16) char lds[32768];
  char* lA = lds;
  char* lB = lds + 16384;
  int tid = threadIdx.x;
  int lane = tid & 63;
  int w = tid >> 6;
  int wr = w >> 1, wc = w & 1;
  int m0 = blockIdx.x * 128;
  int n0 = blockIdx.y * 128;

  f32x4 acc[4][4];
#pragma unroll
  for (int i = 0; i < 4; ++i)
#pragma unroll
    for (int j = 0; j < 4; ++j) acc[i][j] = f32x4{0.f, 0.f, 0.f, 0.f};

  for (int k0 = 0; k0 < KC; k0 += 64) {
    __syncthreads();
#pragma unroll
    for (int i = 0; i < 4; ++i) {
      int c = tid + i * 256;
      int row = c >> 3;
      int cb = (c & 7) << 4;
      int sw = cb ^ ((row & 7) << 4);
      int gr = m0 + row;
      bf16x8 av = {0, 0, 0, 0, 0, 0, 0, 0};
      if (gr < NN)
        av = *reinterpret_cast<const bf16x8*>((const char*)A + ((size_t)gr * KC + k0) * 2 + cb);
      *reinterpret_cast<bf16x8*>(lA + row * 128 + sw) = av;
      bf16x8 wv = *reinterpret_cast<const bf16x8*>(
          (const char*)W + ((size_t)(n0 + row) * KC + k0) * 2 + cb);
      *reinterpret_cast<bf16x8*>(lB + row * 128 + sw) = wv;
    }
    __syncthreads();
#pragma unroll
    for (int ks = 0; ks < 2; ++ks) {
      bf16x8 af[4], bfr[4];
      int ac = ks * 64 + ((lane >> 4) << 4);
#pragma unroll
      for (int f = 0; f < 4; ++f) {
        int ar = wr * 64 + f * 16 + (lane & 15);
        af[f] = *reinterpret_cast<const bf16x8*>(lA + ar * 128 + (ac ^ ((ar & 7) << 4)));
        int br = wc * 64 + f * 16 + (lane & 15);
        bfr[f] = *reinterpret_cast<const bf16x8*>(lB + br * 128 + (ac ^ ((br & 7) << 4)));
      }
#pragma unroll
      for (int fm = 0; fm < 4; ++fm)
#pragma unroll
        for (int fn = 0; fn < 4; ++fn)
          acc[fm][fn] = __builtin_amdgcn_mfma_f32_16x16x32_bf16(af[fm], bfr[fn], acc[fm][fn], 0, 0, 0);
    }
  }

  int nbase = n0 + wc * 64 + (lane & 15);
  float bv[4] = {0.f, 0.f, 0.f, 0.f};
  if constexpr (BIASED) {
#pragma unroll
    for (int fn = 0; fn < 4; ++fn) bv[fn] = bias[nbase + fn * 16];
  }
  float ssum[4] = {0.f, 0.f, 0.f, 0.f}, sqs[4] = {0.f, 0.f, 0.f, 0.f};
#pragma unroll
  for (int fm = 0; fm < 4; ++fm) {
    int mbase = m0 + wr * 64 + fm * 16 + ((lane >> 4) << 2);
#pragma unroll
    for (int j = 0; j < 4; ++j) {
      int m = mbase + j;
      if (m < NN) {
#pragma unroll
        for (int fn = 0; fn < 4; ++fn) {
          float v = acc[fm][fn][j] + bv[fn];
          out[(size_t)m * Ntot + nbase + fn * 16] = f2bf(v);
          if constexpr (STATS) { ssum[fn] += v; sqs[fn] += v * v; }
        }
      }
    }
  }
  if constexpr (STATS) {
#pragma unroll
    for (int fn = 0; fn < 4; ++fn) {
      float s = ssum[fn], q = sqs[fn];
      s += __shfl_xor(s, 16); s += __shfl_xor(s, 32);
      q += __shfl_xor(q, 16); q += __shfl_xor(q, 32);
      if (lane < 16) {
        atomicAdd(&statacc[nbase + fn * 16], s);
        atomicAdd(&statacc[Ntot + nbase + fn * 16], q);
      }
    }
  }
}

// ================= BatchNorm =================
// parallel stats: grid-strided row chunks, LDS reduce, one atomic per col per block
template <int N, bool BF>
__global__ __launch_bounds__(256) void k_bn_stats2(const void* __restrict__ hv,
                                                   float* __restrict__ acc) {
  constexpr int CP = N / 2;
  constexpr int RG = 256 / CP;
  int cp = threadIdx.x % CP, rg = threadIdx.x / CP;
  int rpb = (NN + gridDim.x - 1) / gridDim.x;
  int r0 = blockIdx.x * rpb, r1 = min(r0 + rpb, NN);
  float s0 = 0.f, s1 = 0.f, q0 = 0.f, q1 = 0.f;
  for (int r = r0 + rg; r < r1; r += RG) {
    float v0, v1;
    if constexpr (BF) {
      unsigned int u = ((const unsigned int*)hv)[(size_t)r * CP + cp];
      v0 = bf2f(u & 0xffffu); v1 = bf2f(u >> 16);
    } else {
      float2 u = ((const float2*)hv)[(size_t)r * CP + cp];
      v0 = u.x; v1 = u.y;
    }
    s0 += v0; s1 += v1; q0 += v0 * v0; q1 += v1 * v1;
  }
  __shared__ float l0[256], l1[256], l2[256], l3[256];
  l0[threadIdx.x] = s0; l1[threadIdx.x] = s1; l2[threadIdx.x] = q0; l3[threadIdx.x] = q1;
  __syncthreads();
  if (rg == 0) {
#pragma unroll
    for (int g = 1; g < RG; ++g) {
      s0 += l0[g * CP + cp]; s1 += l1[g * CP + cp];
      q0 += l2[g * CP + cp]; q1 += l3[g * CP + cp];
    }
    atomicAdd(&acc[2 * cp], s0);
    atomicAdd(&acc[2 * cp + 1], s1);
    atomicAdd(&acc[N + 2 * cp], q0);
    atomicAdd(&acc[N + 2 * cp + 1], q1);
  }
}

// pair-wise BN apply + ReLU
template <int N, bool INF32>
__global__ void k_bn_apply2(const void* __restrict__ hv, const float* __restrict__ acc,
                            const float* __restrict__ g, const float* __restrict__ b,
                            unsigned int* __restrict__ out) {
  constexpr int N2 = N / 2;
  int p = blockIdx.x * 256 + threadIdx.x;
  if (p >= NN * N2) return;
  int cp = p % N2;
  int c0 = 2 * cp, c1 = c0 + 1;
  float v0, v1;
  if constexpr (INF32) {
    float2 u = reinterpret_cast<const float2*>(hv)[p];
    v0 = u.x; v1 = u.y;
  } else {
    unsigned int u = reinterpret_cast<const unsigned int*>(hv)[p];
    v0 = bf2f(u & 0xffffu); v1 = bf2f(u >> 16);
  }
  float m0 = acc[c0] * (1.0f / NN);
  float m1 = acc[c1] * (1.0f / NN);
  float sc0 = g[c0] * rsqrtf(acc[N + c0] * (1.0f / NN) - m0 * m0 + BN_EPS);
  float sc1 = g[c1] * rsqrtf(acc[N + c1] * (1.0f / NN) - m1 * m1 + BN_EPS);
  float r0 = fmaxf((v0 - m0) * sc0 + b[c0], 0.f);
  float r1 = fmaxf((v1 - m1) * sc1 + b[c1], 0.f);
  out[p] = (unsigned int)f2bf(r0) | ((unsigned int)f2bf(r1) << 16);
}

// ================= classifier =================
__global__ void k_classifier(const float* __restrict__ emb, const float* __restrict__ Wc,
                             const float* __restrict__ bc, float* __restrict__ logits) {
  int row = blockIdx.x * 256 + threadIdx.x;
  if (row >= NN) return;
  const float* e = emb + (size_t)row * 64;
  float s0 = bc[0], s1 = bc[1];
#pragma unroll
  for (int k = 0; k < 64; ++k) { float v = e[k]; s0 += v * Wc[k]; s1 += v * Wc[64 + k]; }
  logits[row * 2 + 0] = s0;
  logits[row * 2 + 1] = s1;
}

extern "C" void kernel_launch(void* const* d_in, const int* in_sizes, int n_in,
                              void* d_out, int out_size, void* d_ws, size_t ws_size,
                              hipStream_t stream) {
  const float* x   = (const float*)d_in[0];
  const int* ei    = (const int*)d_in[1];
  const float* Wl1 = (const float*)d_in[2];
  const float* Wr1 = (const float*)d_in[3];
  const float* b1  = (const float*)d_in[4];
  const float* Wl2 = (const float*)d_in[5];
  const float* Wr2 = (const float*)d_in[6];
  const float* b2  = (const float*)d_in[7];
  const float* Wle = (const float*)d_in[8];
  const float* Wre = (const float*)d_in[9];
  const float* be  = (const float*)d_in[10];
  const float* g1  = (const float*)d_in[11];
  const float* bt1 = (const float*)d_in[12];
  const float* g2  = (const float*)d_in[13];
  const float* bt2 = (const float*)d_in[14];
  const float* Wc  = (const float*)d_in[15];
  const float* bc  = (const float*)d_in[16];

  const int* src = ei;
  const int* dst = ei + NE;

  char* ws = (char*)d_ws;
  size_t off = 0;
  auto take = [&](size_t bytes) -> char* {
    char* p = ws + off;
    off = (off + bytes + 255) & ~(size_t)255;
    return p;
  };
  int* row_ptr  = (int*)take((size_t)(NN + 1) * 4);
  int* bkt_size = (int*)take(NB * 4);
  int* bkt_base = (int*)take((NB + 1) * 4);
  int* bkt_cur  = (int*)take(NB * 4);
  uint2* pairs  = (uint2*)take((size_t)NE * 8);
  int* col      = (int*)take((size_t)NE * 4);
  unsigned short* w1c = (unsigned short*)take((size_t)256 * 384 * 2);
  unsigned short* w2s = (unsigned short*)take((size_t)256 * 256 * 2);
  unsigned short* w3s = (unsigned short*)take((size_t)128 * 128 * 2);
  float* bnacc  = (float*)take(512 * 4);
  unsigned short* xbf = (unsigned short*)take((size_t)NN * 166 * 2);
  char* P0 = take((size_t)NN * 384 * 2);
  char* P1 = take((size_t)NN * 256 * 2);

  unsigned short* XC1   = (unsigned short*)P0;  // [NN][384]
  unsigned short* h1raw = (unsigned short*)P1;  // [NN][256]
  unsigned short* h1    = (unsigned short*)P0;  // [NN][256]
  unsigned short* z2    = (unsigned short*)P1;  // [NN][256]
  float*          h2raw = (float*)P0;           // [NN][128]
  unsigned short* h2    = (unsigned short*)P1;  // [NN][128]
  unsigned short* z3    = (unsigned short*)P0;  // [NN][128]

  float* logits = (float*)d_out;
  float* emb    = (float*)d_out + (size_t)NN * 2;

  // CSR build (bucketed two-phase)
  hipMemsetAsync(bkt_size, 0, NB * 4, stream);
  k_bhisto<<<(NE + 8191) / 8192, 256, 0, stream>>>(dst, bkt_size);
  k_bscan<<<1, NB, 0, stream>>>(bkt_size, bkt_base, bkt_cur, row_ptr);
  k_bpart<<<(NE + 8191) / 8192, 256, 0, stream>>>(src, dst, bkt_cur, pairs);
  k_bscatter<<<NB, NB, 0, stream>>>(pairs, bkt_base, row_ptr, col);

  // conversions + weight packing
  k_cvt_bf4<<<(NN * 166 / 4 + 255) / 256, 256, 0, stream>>>(x, xbf, NN * 166 / 4);
  k_pack_w1<<<(256 * 384 + 255) / 256, 256, 0, stream>>>(Wl1, Wr1, w1c);
  k_pack_wn<<<(256 * 256 + 255) / 256, 256, 0, stream>>>(Wl2, Wr2, w2s, 256, 128);
  k_pack_wn<<<(128 * 128 + 255) / 256, 256, 0, stream>>>(Wle, Wre, w3s, 128, 64);

  // ---- layer 1: XC1 = [agg(x) | x] @ w1c + b1 -> h1raw (+fused BN stats); BN+ReLU -> h1 ----
  k_pack_xb<<<NN, 224, 0, stream>>>(x, XC1);
  k_aggb<166, 4, false, true><<<(NN + 3) / 4, 256, 0, stream>>>(
      (const unsigned int*)xbf, 83, row_ptr, col, nullptr, 0, nullptr, XC1, 192);
  hipMemsetAsync(bnacc, 0, 512 * 4, stream);
  {
    dim3 g((NN + 127) / 128, 2);
    k_gemm_mfma<true, true><<<g, 256, 0, stream>>>(XC1, 384, w1c, b1, h1raw, 256, bnacc);
  }
  k_bn_apply2<256, false><<<(NN * 128 + 255) / 256, 256, 0, stream>>>(
      h1raw, bnacc, g1, bt1, (unsigned int*)h1);

  // ---- layer 2: z2 = h1 @ [Wl2;Wr2]^T; h2raw = agg(z2[:,:128]) + z2[:,128:] + b2 ----
  {
    dim3 g((NN + 127) / 128, 2);
    k_gemm_mfma<false, false><<<g, 256, 0, stream>>>(h1, 256, w2s, nullptr, z2, 256, nullptr);
  }
  k_aggb<128, 8, true, false><<<(NN + 3) / 4, 256, 0, stream>>>(
      (const unsigned int*)z2, 128, row_ptr, col, (const unsigned int*)z2 + 64, 128, b2, h2raw, 128);
  hipMemsetAsync(bnacc, 0, 512 * 4, stream);
  k_bn_stats2<128, false><<<512, 256, 0, stream>>>(h2raw, bnacc);
  k_bn_apply2<128, true><<<(NN * 64 + 255) / 256, 256, 0, stream>>>(
      h2raw, bnacc, g2, bt2, (unsigned int*)h2);

  // ---- layer 3: z3 = h2 @ [Wle;Wre]^T; emb = agg(z3[:,:64]) + z3[:,64:] + be ----
  {
    dim3 g((NN + 127) / 128, 1);
    k_gemm_mfma<false, false><<<g, 256, 0, stream>>>(h2, 128, w3s, nullptr, z3, 128, nullptr);
  }
  k_aggb<64, 8, true, false><<<(NN + 7) / 8, 256, 0, stream>>>(
      (const unsigned int*)z3, 64, row_ptr, col, (const unsigned int*)z3 + 32, 64, be, emb, 64);

  k_classifier<<<(NN + 255) / 256, 256, 0, stream>>>(emb, Wc, bc, logits);
}

// Round 8
// 338.174 us; speedup vs baseline: 99.5757x; 1.0455x over previous
//
#include <hip/hip_runtime.h>

#define NN 50000
#define NE 800000
#define NB 256
#define BNODES ((NN + NB - 1) / NB)  // 196 nodes per bucket
static constexpr float BN_EPS = 1e-5f;

typedef __attribute__((ext_vector_type(8))) short bf16x8;
typedef __attribute__((ext_vector_type(4))) float f32x4;

__device__ inline unsigned short f2bf(float f) {
  unsigned int u = __float_as_uint(f);
  return (unsigned short)((u + 0x7FFFu + ((u >> 16) & 1u)) >> 16);
}
__device__ inline float bf2f(unsigned int h) {
  return __uint_as_float(h << 16);
}
__device__ inline void gl_lds16(const char* g, char* l) {
  __builtin_amdgcn_global_load_lds((const __attribute__((address_space(1))) void*)g,
                                   (__attribute__((address_space(3))) void*)l, 16, 0, 0);
}

// ================= CSR build: bucketed two-phase =================
__global__ void k_bhisto(const int* __restrict__ dst, int* __restrict__ bsize) {
  __shared__ int cnt[NB];
  int t = threadIdx.x;
  cnt[t] = 0;
  __syncthreads();
  int e0 = blockIdx.x * 8192 + t;
#pragma unroll
  for (int i = 0; i < 32; ++i) {
    int e = e0 + i * 256;
    if (e < NE) atomicAdd(&cnt[dst[e] / BNODES], 1);
  }
  __syncthreads();
  if (cnt[t]) atomicAdd(&bsize[t], cnt[t]);
}

__global__ void k_bscan(const int* __restrict__ bsize, int* __restrict__ bbase,
                        int* __restrict__ bcur, int* __restrict__ row_ptr) {
  __shared__ int ts[NB];
  int t = threadIdx.x;
  int v = bsize[t];
  ts[t] = v;
  __syncthreads();
#pragma unroll
  for (int off = 1; off < NB; off <<= 1) {
    int u = (t >= off) ? ts[t - off] : 0;
    __syncthreads();
    ts[t] += u;
    __syncthreads();
  }
  bbase[t] = ts[t] - v;
  bcur[t] = ts[t] - v;
  if (t == NB - 1) { bbase[NB] = ts[t]; row_ptr[NN] = NE; }
}

__global__ void k_bpart(const int* __restrict__ src, const int* __restrict__ dst,
                        int* __restrict__ bcur, uint2* __restrict__ pairs) {
  __shared__ int cnt[NB], lbase[NB], lcur[NB];
  int t = threadIdx.x;
  cnt[t] = 0;
  __syncthreads();
  int e0 = blockIdx.x * 8192 + t;
#pragma unroll
  for (int i = 0; i < 32; ++i) {
    int e = e0 + i * 256;
    if (e < NE) atomicAdd(&cnt[dst[e] / BNODES], 1);
  }
  __syncthreads();
  lbase[t] = cnt[t] ? atomicAdd(&bcur[t], cnt[t]) : 0;
  lcur[t] = 0;
  __syncthreads();
#pragma unroll
  for (int i = 0; i < 32; ++i) {
    int e = e0 + i * 256;
    if (e < NE) {
      int d = dst[e];
      int b = d / BNODES;
      int p = atomicAdd(&lcur[b], 1);
      pairs[(size_t)lbase[b] + p] = uint2{(unsigned)src[e], (unsigned)d};
    }
  }
}

__global__ void k_bscatter(const uint2* __restrict__ pairs, const int* __restrict__ bbase,
                           int* __restrict__ row_ptr, int* __restrict__ col) {
  __shared__ int dcnt[NB], ts[NB], doff[NB], dcur[NB];
  int t = threadIdx.x;
  int b = blockIdx.x;
  int n0 = b * BNODES;
  int ncnt = min(NN - n0, BNODES);
  int e0 = bbase[b], e1 = bbase[b + 1];
  dcnt[t] = 0;
  __syncthreads();
  for (int e = e0 + t; e < e1; e += 256) atomicAdd(&dcnt[pairs[e].y - n0], 1);
  __syncthreads();
  ts[t] = dcnt[t];
  __syncthreads();
#pragma unroll
  for (int off = 1; off < NB; off <<= 1) {
    int u = (t >= off) ? ts[t - off] : 0;
    __syncthreads();
    ts[t] += u;
    __syncthreads();
  }
  doff[t] = ts[t] - dcnt[t];
  dcur[t] = 0;
  if (t < ncnt) row_ptr[n0 + t] = e0 + doff[t];
  __syncthreads();
  for (int e = e0 + t; e < e1; e += 256) {
    uint2 pr = pairs[e];
    int ld = pr.y - n0;
    int p = atomicAdd(&dcur[ld], 1);
    col[e0 + doff[ld] + p] = (int)pr.x;
  }
}

// ================= conversions / packing =================
__global__ void k_cvt_bf4(const float* __restrict__ in, unsigned short* __restrict__ out, int n4) {
  int i = blockIdx.x * 256 + threadIdx.x;
  if (i >= n4) return;
  float4 v = reinterpret_cast<const float4*>(in)[i];
  unsigned short o[4] = {f2bf(v.x), f2bf(v.y), f2bf(v.z), f2bf(v.w)};
  *reinterpret_cast<ulong1*>(out + 4 * (size_t)i) = *reinterpret_cast<ulong1*>(o);
}

__global__ void k_pack_xb(const float* __restrict__ x, unsigned short* __restrict__ XC1) {
  int row = blockIdx.x;
  int t = threadIdx.x;
  if (t >= 218) return;
  int c = 166 + t;
  float v = (c >= 192 && c < 358) ? x[(size_t)row * 166 + (c - 192)] : 0.f;
  XC1[(size_t)row * 384 + c] = f2bf(v);
}

__global__ void k_pack_w1(const float* __restrict__ Wl, const float* __restrict__ Wr,
                          unsigned short* __restrict__ WC) {
  int idx = blockIdx.x * 256 + threadIdx.x;
  if (idx >= 256 * 384) return;
  int n = idx / 384, k = idx - n * 384;
  float v = 0.f;
  if (k < 166) v = Wl[(size_t)n * 166 + k];
  else if (k >= 192 && k < 358) v = Wr[(size_t)n * 166 + (k - 192)];
  WC[idx] = f2bf(v);
}

__global__ void k_pack_wn(const float* __restrict__ Wl, const float* __restrict__ Wr,
                          unsigned short* __restrict__ WC, int K, int Nh) {
  int idx = blockIdx.x * 256 + threadIdx.x;
  if (idx >= 2 * Nh * K) return;
  int n = idx / K, k = idx - n * K;
  WC[idx] = f2bf(n < Nh ? Wl[(size_t)n * K + k] : Wr[(size_t)(n - Nh) * K + k]);
}

// ================= bf16 mean aggregation (optional fused classifier) =================
template <int D, int U, bool FUSE, bool OUTBF, bool CLS>
__global__ __launch_bounds__(256) void k_aggb(
    const unsigned int* __restrict__ feat, int fsu,
    const int* __restrict__ row_ptr, const int* __restrict__ col,
    const unsigned int* __restrict__ self, int ssu,
    const float* __restrict__ bias,
    void* __restrict__ outv, int osu,
    const float* __restrict__ Wc, const float* __restrict__ bc,
    float* __restrict__ logits) {
  constexpr int D2 = D / 2;
  constexpr int LPN = (D2 < 64) ? D2 : 64;
  constexpr int NPB = 256 / LPN;
  constexpr int C = (D2 + LPN - 1) / LPN;
  int node = blockIdx.x * NPB + threadIdx.x / LPN;
  if (node >= NN) return;
  int lane = threadIdx.x % LPN;
  int beg = row_ptr[node], end = row_ptr[node + 1];
  float ax[C], ay[C];
#pragma unroll
  for (int c = 0; c < C; ++c) { ax[c] = 0.f; ay[c] = 0.f; }

  int j = beg;
  for (; j + U <= end; j += U) {
    const unsigned int* fp[U];
#pragma unroll
    for (int u = 0; u < U; ++u) fp[u] = feat + (size_t)col[j + u] * fsu;
#pragma unroll
    for (int c = 0; c < C; ++c) {
      int p = lane + c * LPN;
      unsigned int t[U];
#pragma unroll
      for (int u = 0; u < U; ++u) t[u] = (p < D2) ? fp[u][p] : 0u;
#pragma unroll
      for (int u = 0; u < U; ++u) {
        ax[c] += bf2f(t[u] & 0xffffu);
        ay[c] += bf2f(t[u] >> 16);
      }
    }
  }
  for (; j < end; ++j) {
    const unsigned int* fr = feat + (size_t)col[j] * fsu;
#pragma unroll
    for (int c = 0; c < C; ++c) {
      int p = lane + c * LPN;
      if (p < D2) {
        unsigned int t = fr[p];
        ax[c] += bf2f(t & 0xffffu);
        ay[c] += bf2f(t >> 16);
      }
    }
  }
  float inv = 1.0f / fmaxf((float)(end - beg), 1.0f);
  float s0 = 0.f, s1 = 0.f;
#pragma unroll
  for (int c = 0; c < C; ++c) {
    int p = lane + c * LPN;
    if (p < D2) {
      float vx = ax[c] * inv, vy = ay[c] * inv;
      if constexpr (FUSE) {
        unsigned int s = self[(size_t)node * ssu + p];
        vx += bf2f(s & 0xffffu) + bias[2 * p];
        vy += bf2f(s >> 16) + bias[2 * p + 1];
      }
      if constexpr (OUTBF) {
        unsigned int o = (unsigned int)f2bf(vx) | ((unsigned int)f2bf(vy) << 16);
        ((unsigned int*)outv)[(size_t)node * osu + p] = o;
      } else {
        float2 o{vx, vy};
        *reinterpret_cast<float2*>((float*)outv + (size_t)node * osu + 2 * p) = o;
      }
      if constexpr (CLS) {
        s0 += vx * Wc[2 * p] + vy * Wc[2 * p + 1];
        s1 += vx * Wc[64 + 2 * p] + vy * Wc[64 + 2 * p + 1];
      }
    }
  }
  if constexpr (CLS) {
#pragma unroll
    for (int m = 1; m < LPN; m <<= 1) {
      s0 += __shfl_xor(s0, m);
      s1 += __shfl_xor(s1, m);
    }
    if (lane == 0) {
      logits[node * 2 + 0] = s0 + bc[0];
      logits[node * 2 + 1] = s1 + bc[1];
    }
  }
}

// ================= bf16 MFMA GEMM, 2-phase pipelined global_load_lds =================
// 128x128 tile, BK=64, 4 waves, double-buffered LDS (2 x 32KB), pre-swizzled source.
template <bool BIASED, bool STATS>
__global__ __launch_bounds__(256) void k_gemm_mfma(
    const unsigned short* __restrict__ A, int KC,
    const unsigned short* __restrict__ W,
    const float* __restrict__ bias,
    unsigned short* __restrict__ out, int Ntot,
    float* __restrict__ statacc) {
  __shared__ __align__(16) char lds[65536];
  int tid = threadIdx.x;
  int lane = tid & 63;
  int w = tid >> 6;
  int wr = w >> 1, wc = w & 1;
  int m0 = blockIdx.x * 128;
  int n0 = blockIdx.y * 128;

  // staging geometry: instr (w,i) covers rows w*32+i*8 .. +7; lane l -> row +(l>>3), byte col (l&7)*16
  int srow = lane >> 3;            // row&7 within chunk (== LDS row & 7)
  int scol = (lane & 7) << 4;      // dest byte col 0..112
  int ssw = scol ^ (srow << 4);    // inverse-swizzled SOURCE byte col
  const char* Ab = (const char*)A;
  const char* Wb = (const char*)W;

  f32x4 acc[4][4];
#pragma unroll
  for (int i = 0; i < 4; ++i)
#pragma unroll
    for (int j = 0; j < 4; ++j) acc[i][j] = f32x4{0.f, 0.f, 0.f, 0.f};

  auto stage = [&](int buf, int k0) {
    char* dst = lds + buf * 32768 + w * 4096;
#pragma unroll
    for (int i = 0; i < 4; ++i) {
      int row = w * 32 + i * 8 + srow;
      int ga = m0 + row;
      ga = ga < NN ? ga : NN - 1;  // clamp: garbage rows never stored
      gl_lds16(Ab + ((size_t)ga * KC + k0) * 2 + ssw, dst + i * 1024);
      gl_lds16(Wb + ((size_t)(n0 + row) * KC + k0) * 2 + ssw, dst + 16384 + i * 1024);
    }
  };
  auto compute = [&](int buf) {
    char* lA = lds + buf * 32768;
    char* lB = lA + 16384;
#pragma unroll
    for (int ks = 0; ks < 2; ++ks) {
      bf16x8 af[4], bfr[4];
      int ac = ks * 64 + ((lane >> 4) << 4);
#pragma unroll
      for (int f = 0; f < 4; ++f) {
        int ar = wr * 64 + f * 16 + (lane & 15);
        af[f] = *reinterpret_cast<const bf16x8*>(lA + ar * 128 + (ac ^ ((ar & 7) << 4)));
        int br = wc * 64 + f * 16 + (lane & 15);
        bfr[f] = *reinterpret_cast<const bf16x8*>(lB + br * 128 + (ac ^ ((br & 7) << 4)));
      }
#pragma unroll
      for (int fm = 0; fm < 4; ++fm)
#pragma unroll
        for (int fn = 0; fn < 4; ++fn)
          acc[fm][fn] = __builtin_amdgcn_mfma_f32_16x16x32_bf16(af[fm], bfr[fn], acc[fm][fn], 0, 0, 0);
    }
  };

  int nt = KC >> 6;
  stage(0, 0);
  __syncthreads();
  int cur = 0;
  for (int t = 0; t < nt; ++t) {
    if (t + 1 < nt) stage(cur ^ 1, (t + 1) << 6);  // prefetch overlaps compute
    compute(cur);
    __syncthreads();
    cur ^= 1;
  }

  int nbase = n0 + wc * 64 + (lane & 15);
  float bv[4] = {0.f, 0.f, 0.f, 0.f};
  if constexpr (BIASED) {
#pragma unroll
    for (int fn = 0; fn < 4; ++fn) bv[fn] = bias[nbase + fn * 16];
  }
  float ssum[4] = {0.f, 0.f, 0.f, 0.f}, sqs[4] = {0.f, 0.f, 0.f, 0.f};
#pragma unroll
  for (int fm = 0; fm < 4; ++fm) {
    int mbase = m0 + wr * 64 + fm * 16 + ((lane >> 4) << 2);
#pragma unroll
    for (int j = 0; j < 4; ++j) {
      int m = mbase + j;
      if (m < NN) {
#pragma unroll
        for (int fn = 0; fn < 4; ++fn) {
          float v = acc[fm][fn][j] + bv[fn];
          out[(size_t)m * Ntot + nbase + fn * 16] = f2bf(v);
          if constexpr (STATS) { ssum[fn] += v; sqs[fn] += v * v; }
        }
      }
    }
  }
  if constexpr (STATS) {
#pragma unroll
    for (int fn = 0; fn < 4; ++fn) {
      float s = ssum[fn], q = sqs[fn];
      s += __shfl_xor(s, 16); s += __shfl_xor(s, 32);
      q += __shfl_xor(q, 16); q += __shfl_xor(q, 32);
      if (lane < 16) {
        atomicAdd(&statacc[nbase + fn * 16], s);
        atomicAdd(&statacc[Ntot + nbase + fn * 16], q);
      }
    }
  }
}

// ================= BatchNorm =================
template <int N, bool BF>
__global__ __launch_bounds__(256) void k_bn_stats2(const void* __restrict__ hv,
                                                   float* __restrict__ acc) {
  constexpr int CP = N / 2;
  constexpr int RG = 256 / CP;
  int cp = threadIdx.x % CP, rg = threadIdx.x / CP;
  int rpb = (NN + gridDim.x - 1) / gridDim.x;
  int r0 = blockIdx.x * rpb, r1 = min(r0 + rpb, NN);
  float s0 = 0.f, s1 = 0.f, q0 = 0.f, q1 = 0.f;
  for (int r = r0 + rg; r < r1; r += RG) {
    float v0, v1;
    if constexpr (BF) {
      unsigned int u = ((const unsigned int*)hv)[(size_t)r * CP + cp];
      v0 = bf2f(u & 0xffffu); v1 = bf2f(u >> 16);
    } else {
      float2 u = ((const float2*)hv)[(size_t)r * CP + cp];
      v0 = u.x; v1 = u.y;
    }
    s0 += v0; s1 += v1; q0 += v0 * v0; q1 += v1 * v1;
  }
  __shared__ float l0[256], l1[256], l2[256], l3[256];
  l0[threadIdx.x] = s0; l1[threadIdx.x] = s1; l2[threadIdx.x] = q0; l3[threadIdx.x] = q1;
  __syncthreads();
  if (rg == 0) {
#pragma unroll
    for (int g = 1; g < RG; ++g) {
      s0 += l0[g * CP + cp]; s1 += l1[g * CP + cp];
      q0 += l2[g * CP + cp]; q1 += l3[g * CP + cp];
    }
    atomicAdd(&acc[2 * cp], s0);
    atomicAdd(&acc[2 * cp + 1], s1);
    atomicAdd(&acc[N + 2 * cp], q0);
    atomicAdd(&acc[N + 2 * cp + 1], q1);
  }
}

template <int N, bool INF32>
__global__ void k_bn_apply2(const void* __restrict__ hv, const float* __restrict__ acc,
                            const float* __restrict__ g, const float* __restrict__ b,
                            unsigned int* __restrict__ out) {
  constexpr int N2 = N / 2;
  int p = blockIdx.x * 256 + threadIdx.x;
  if (p >= NN * N2) return;
  int cp = p % N2;
  int c0 = 2 * cp, c1 = c0 + 1;
  float v0, v1;
  if constexpr (INF32) {
    float2 u = reinterpret_cast<const float2*>(hv)[p];
    v0 = u.x; v1 = u.y;
  } else {
    unsigned int u = reinterpret_cast<const unsigned int*>(hv)[p];
    v0 = bf2f(u & 0xffffu); v1 = bf2f(u >> 16);
  }
  float m0 = acc[c0] * (1.0f / NN);
  float m1 = acc[c1] * (1.0f / NN);
  float sc0 = g[c0] * rsqrtf(acc[N + c0] * (1.0f / NN) - m0 * m0 + BN_EPS);
  float sc1 = g[c1] * rsqrtf(acc[N + c1] * (1.0f / NN) - m1 * m1 + BN_EPS);
  float r0 = fmaxf((v0 - m0) * sc0 + b[c0], 0.f);
  float r1 = fmaxf((v1 - m1) * sc1 + b[c1], 0.f);
  out[p] = (unsigned int)f2bf(r0) | ((unsigned int)f2bf(r1) << 16);
}

extern "C" void kernel_launch(void* const* d_in, const int* in_sizes, int n_in,
                              void* d_out, int out_size, void* d_ws, size_t ws_size,
                              hipStream_t stream) {
  const float* x   = (const float*)d_in[0];
  const int* ei    = (const int*)d_in[1];
  const float* Wl1 = (const float*)d_in[2];
  const float* Wr1 = (const float*)d_in[3];
  const float* b1  = (const float*)d_in[4];
  const float* Wl2 = (const float*)d_in[5];
  const float* Wr2 = (const float*)d_in[6];
  const float* b2  = (const float*)d_in[7];
  const float* Wle = (const float*)d_in[8];
  const float* Wre = (const float*)d_in[9];
  const float* be  = (const float*)d_in[10];
  const float* g1  = (const float*)d_in[11];
  const float* bt1 = (const float*)d_in[12];
  const float* g2  = (const float*)d_in[13];
  const float* bt2 = (const float*)d_in[14];
  const float* Wc  = (const float*)d_in[15];
  const float* bc  = (const float*)d_in[16];

  const int* src = ei;
  const int* dst = ei + NE;

  char* ws = (char*)d_ws;
  size_t off = 0;
  auto take = [&](size_t bytes) -> char* {
    char* p = ws + off;
    off = (off + bytes + 255) & ~(size_t)255;
    return p;
  };
  int* row_ptr  = (int*)take((size_t)(NN + 1) * 4);
  int* bkt_size = (int*)take(NB * 4);
  int* bkt_base = (int*)take((NB + 1) * 4);
  int* bkt_cur  = (int*)take(NB * 4);
  uint2* pairs  = (uint2*)take((size_t)NE * 8);
  int* col      = (int*)take((size_t)NE * 4);
  unsigned short* w1c = (unsigned short*)take((size_t)256 * 384 * 2);
  unsigned short* w2s = (unsigned short*)take((size_t)256 * 256 * 2);
  unsigned short* w3s = (unsigned short*)take((size_t)128 * 128 * 2);
  float* bnacc  = (float*)take(512 * 4);
  unsigned short* xbf = (unsigned short*)take((size_t)NN * 166 * 2);
  char* P0 = take((size_t)NN * 384 * 2);
  char* P1 = take((size_t)NN * 256 * 2);

  unsigned short* XC1   = (unsigned short*)P0;  // [NN][384]
  unsigned short* h1raw = (unsigned short*)P1;  // [NN][256]
  unsigned short* h1    = (unsigned short*)P0;  // [NN][256]
  unsigned short* z2    = (unsigned short*)P1;  // [NN][256]
  float*          h2raw = (float*)P0;           // [NN][128]
  unsigned short* h2    = (unsigned short*)P1;  // [NN][128]
  unsigned short* z3    = (unsigned short*)P0;  // [NN][128]

  float* logits = (float*)d_out;
  float* emb    = (float*)d_out + (size_t)NN * 2;

  // CSR build (bucketed two-phase)
  hipMemsetAsync(bkt_size, 0, NB * 4, stream);
  k_bhisto<<<(NE + 8191) / 8192, 256, 0, stream>>>(dst, bkt_size);
  k_bscan<<<1, NB, 0, stream>>>(bkt_size, bkt_base, bkt_cur, row_ptr);
  k_bpart<<<(NE + 8191) / 8192, 256, 0, stream>>>(src, dst, bkt_cur, pairs);
  k_bscatter<<<NB, NB, 0, stream>>>(pairs, bkt_base, row_ptr, col);

  // conversions + weight packing
  k_cvt_bf4<<<(NN * 166 / 4 + 255) / 256, 256, 0, stream>>>(x, xbf, NN * 166 / 4);
  k_pack_w1<<<(256 * 384 + 255) / 256, 256, 0, stream>>>(Wl1, Wr1, w1c);
  k_pack_wn<<<(256 * 256 + 255) / 256, 256, 0, stream>>>(Wl2, Wr2, w2s, 256, 128);
  k_pack_wn<<<(128 * 128 + 255) / 256, 256, 0, stream>>>(Wle, Wre, w3s, 128, 64);

  // ---- layer 1: XC1 = [agg(x) | x] @ w1c + b1 -> h1raw (+fused BN stats); BN+ReLU -> h1 ----
  k_pack_xb<<<NN, 224, 0, stream>>>(x, XC1);
  k_aggb<166, 4, false, true, false><<<(NN + 3) / 4, 256, 0, stream>>>(
      (const unsigned int*)xbf, 83, row_ptr, col, nullptr, 0, nullptr, XC1, 192,
      nullptr, nullptr, nullptr);
  hipMemsetAsync(bnacc, 0, 512 * 4, stream);
  {
    dim3 g((NN + 127) / 128, 2);
    k_gemm_mfma<true, true><<<g, 256, 0, stream>>>(XC1, 384, w1c, b1, h1raw, 256, bnacc);
  }
  k_bn_apply2<256, false><<<(NN * 128 + 255) / 256, 256, 0, stream>>>(
      h1raw, bnacc, g1, bt1, (unsigned int*)h1);

  // ---- layer 2: z2 = h1 @ [Wl2;Wr2]^T; h2raw = agg(z2[:,:128]) + z2[:,128:] + b2 ----
  {
    dim3 g((NN + 127) / 128, 2);
    k_gemm_mfma<false, false><<<g, 256, 0, stream>>>(h1, 256, w2s, nullptr, z2, 256, nullptr);
  }
  k_aggb<128, 8, true, false, false><<<(NN + 3) / 4, 256, 0, stream>>>(
      (const unsigned int*)z2, 128, row_ptr, col, (const unsigned int*)z2 + 64, 128, b2, h2raw, 128,
      nullptr, nullptr, nullptr);
  hipMemsetAsync(bnacc, 0, 512 * 4, stream);
  k_bn_stats2<128, false><<<512, 256, 0, stream>>>(h2raw, bnacc);
  k_bn_apply2<128, true><<<(NN * 64 + 255) / 256, 256, 0, stream>>>(
      h2raw, bnacc, g2, bt2, (unsigned int*)h2);

  // ---- layer 3: z3 = h2 @ [Wle;Wre]^T; emb = agg(z3[:,:64]) + z3[:,64:] + be; fused classifier ----
  {
    dim3 g((NN + 127) / 128, 1);
    k_gemm_mfma<false, false><<<g, 256, 0, stream>>>(h2, 128, w3s, nullptr, z3, 128, nullptr);
  }
  k_aggb<64, 8, true, false, true><<<(NN + 7) / 8, 256, 0, stream>>>(
      (const unsigned int*)z3, 64, row_ptr, col, (const unsigned int*)z3 + 32, 64, be, emb, 64,
      Wc, bc, logits);
}